// Round 7
// baseline (789.227 us; speedup 1.0000x reference)
//
#include <hip/hip_runtime.h>
#include <math.h>

#define TPTS 200000
#define BB 2
#define NPTS (BB*TPTS)
#define GRID3 32768
#define BG 65536   // BB * GRID3

// cell id: must match reference fp32 arithmetic exactly
__device__ __forceinline__ int cellof(float p0, float p1, float p2, int t)
{
  const float DEN = (float)(1.0 + 0.1 + 1e-3);
  const float HI  = (float)(1.0 - 1e-3);
  float n0 = fminf(fmaxf(p0/DEN + 0.5f, 0.f), HI);
  float n1 = fminf(fmaxf(p1/DEN + 0.5f, 0.f), HI);
  float n2 = fminf(fmaxf(p2/DEN + 0.5f, 0.f), HI);
  int c0 = (int)floorf(n0*32.f), c1 = (int)floorf(n1*32.f), c2 = (int)floorf(n2*32.f);
  return c0 + 32*(c1 + 32*c2) + (t >= TPTS ? GRID3 : 0);
}

__global__ __launch_bounds__(256) void k_hist(
    const float* __restrict__ p, int* __restrict__ gbuf, int* __restrict__ hist)
{
  int t = blockIdx.x*256 + threadIdx.x;
  if (t >= NPTS) return;
  int g = cellof(p[3*t], p[3*t+1], p[3*t+2], t);
  gbuf[t] = g;
  atomicAdd(hist + g, 1);
}

// single-block exclusive scan of hist[BG] -> start[BG+1], cursor[BG]
__global__ __launch_bounds__(1024) void k_scan(
    const int* __restrict__ hist, int* __restrict__ start, int* __restrict__ cursor)
{
  __shared__ int sums[1024];
  const int tid = threadIdx.x;
  const int base = tid * (BG/1024);
  int acc = 0;
#pragma unroll 4
  for (int k = 0; k < BG/1024; k++) acc += hist[base+k];
  sums[tid] = acc;
  __syncthreads();
  for (int off = 1; off < 1024; off <<= 1) {
    int v = sums[tid];
    int u = (tid >= off) ? sums[tid-off] : 0;
    __syncthreads();
    sums[tid] = v + u;
    __syncthreads();
  }
  int run = (tid > 0) ? sums[tid-1] : 0;
#pragma unroll 4
  for (int k = 0; k < BG/1024; k++) {
    start[base+k] = run; cursor[base+k] = run;
    run += hist[base+k];
  }
  if (tid == 1023) start[BG] = sums[1023];
}

// permute raw coords into sorted order
__global__ __launch_bounds__(256) void k_scatter(
    const float* __restrict__ p, const int* __restrict__ gbuf,
    int* __restrict__ cursor, float* __restrict__ p_sorted, int* __restrict__ gsort)
{
  int t = blockIdx.x*256 + threadIdx.x;
  if (t >= NPTS) return;
  int g = gbuf[t];
  int slot = atomicAdd(cursor + g, 1);
  gsort[slot] = g;
  p_sorted[3*slot]   = p[3*t];
  p_sorted[3*slot+1] = p[3*t+1];
  p_sorted[3*slot+2] = p[3*t+2];
}

// posenc + fc_pos -> xbuf (SoA [64][NPTS]), sorted order, rolled l-loop
__global__ __launch_bounds__(256) void k_stage0(
    const float* __restrict__ ps,
    const float* __restrict__ Wp, const float* __restrict__ bp,
    float* __restrict__ xbuf)
{
  int i = blockIdx.x*256 + threadIdx.x;
  if (i >= NPTS) return;
  float p0 = ps[3*i], p1 = ps[3*i+1], p2 = ps[3*i+2];

  float x[64];
#pragma unroll
  for (int j = 0; j < 64; j++) x[j] = bp[j];

  float u0 = 2.f*p0 - 1.f, u1 = 2.f*p1 - 1.f, u2 = 2.f*p2 - 1.f;
  const float PIF = 3.14159265358979323846f;
#pragma unroll 1
  for (int l = 0; l < 10; l++) {
    float uu[3] = {u0, u1, u2};
#pragma unroll
    for (int d = 0; d < 3; d++) {
      float r = uu[d] - 2.f*rintf(0.5f*uu[d]);   // exact mod-2 reduction
      float s, c;
      __sincosf(PIF*r, &s, &c);
      const float* wsr = Wp + (l*6 + d)*64;      // sin row
      const float* wcr = Wp + (l*6 + 3 + d)*64;  // cos row
#pragma unroll
      for (int j = 0; j < 64; j++) x[j] = fmaf(s, wsr[j], fmaf(c, wcr[j], x[j]));
    }
    u0 *= 2.f; u1 *= 2.f; u2 *= 2.f;
  }
#pragma unroll
  for (int j = 0; j < 64; j++) xbuf[(size_t)j*NPTS + i] = x[j];
}

// resblock0: K=64 streamed from xbuf, unroll 16 (deep MLP window), s_load weights
__global__ __launch_bounds__(256, 4) void k_res0(
    const float* __restrict__ xbuf,
    const float* __restrict__ w0, const float* __restrict__ b0,
    const float* __restrict__ w1, const float* __restrict__ b1,
    const float* __restrict__ ws,
    float* __restrict__ net)
{
  int i = blockIdx.x*256 + threadIdx.x;
  if (i >= NPTS) return;
  float h[32], y[32];
#pragma unroll
  for (int j = 0; j < 32; j++) { h[j] = b0[j]; y[j] = b1[j]; }
#pragma unroll 16
  for (int k = 0; k < 64; k++) {
    float xv = xbuf[(size_t)k*NPTS + i];
    float xr = fmaxf(xv, 0.f);
    const float* w0r = w0 + k*32;
    const float* wsr = ws + k*32;
#pragma unroll
    for (int j = 0; j < 32; j++) {
      h[j] = fmaf(xr, w0r[j], h[j]);
      y[j] = fmaf(xv, wsr[j], y[j]);
    }
  }
#pragma unroll
  for (int j = 0; j < 32; j++) h[j] = fmaxf(h[j], 0.f);
#pragma unroll
  for (int k = 0; k < 32; k++) {
    float hv = h[k];
#pragma unroll
    for (int j = 0; j < 32; j++) y[j] = fmaf(hv, w1[k*32+j], y[j]);
  }
#pragma unroll
  for (int j = 0; j < 32; j++) net[(size_t)j*NPTS + i] = y[j];
}

// middle stages: own 32 ch from net (coalesced) + pooled 32 ch; unroll 16
__global__ __launch_bounds__(256, 4) void k_stage(
    float* __restrict__ net, const int* __restrict__ gsort,
    const float* __restrict__ pooled,
    const float* __restrict__ w0, const float* __restrict__ b0,
    const float* __restrict__ w1, const float* __restrict__ b1,
    const float* __restrict__ ws)
{
  int i = blockIdx.x*256 + threadIdx.x;
  if (i >= NPTS) return;
  int g = gsort[i];
  float h[32], y[32];
#pragma unroll
  for (int j = 0; j < 32; j++) { h[j] = b0[j]; y[j] = b1[j]; }
#pragma unroll 16
  for (int k = 0; k < 32; k++) {
    float xv = net[(size_t)k*NPTS + i];
    float xr = fmaxf(xv, 0.f);
    const float* w0r = w0 + k*32;
    const float* wsr = ws + k*32;
#pragma unroll
    for (int j = 0; j < 32; j++) {
      h[j] = fmaf(xr, w0r[j], h[j]);
      y[j] = fmaf(xv, wsr[j], y[j]);
    }
  }
#pragma unroll 16
  for (int k = 0; k < 32; k++) {
    float xv = pooled[(size_t)k*BG + g];
    float xr = fmaxf(xv, 0.f);
    const float* w0r = w0 + (32+k)*32;
    const float* wsr = ws + (32+k)*32;
#pragma unroll
    for (int j = 0; j < 32; j++) {
      h[j] = fmaf(xr, w0r[j], h[j]);
      y[j] = fmaf(xv, wsr[j], y[j]);
    }
  }
#pragma unroll
  for (int j = 0; j < 32; j++) h[j] = fmaxf(h[j], 0.f);
#pragma unroll
  for (int k = 0; k < 32; k++) {
    float hv = h[k];
#pragma unroll
    for (int j = 0; j < 32; j++) y[j] = fmaf(hv, w1[k*32+j], y[j]);
  }
#pragma unroll
  for (int j = 0; j < 32; j++) net[(size_t)j*NPTS + i] = y[j];
}

// last stage + fc_c, fc_c from registers (no net round-trip); stores only c
__global__ __launch_bounds__(256, 4) void k_final(
    float* __restrict__ net, const int* __restrict__ gsort,
    const float* __restrict__ pooled,
    const float* __restrict__ w0, const float* __restrict__ b0,
    const float* __restrict__ w1, const float* __restrict__ b1,
    const float* __restrict__ ws,
    const float* __restrict__ wc, const float* __restrict__ bc)
{
  int i = blockIdx.x*256 + threadIdx.x;
  if (i >= NPTS) return;
  int g = gsort[i];
  float h[32], y[32];
#pragma unroll
  for (int j = 0; j < 32; j++) { h[j] = b0[j]; y[j] = b1[j]; }
#pragma unroll 16
  for (int k = 0; k < 32; k++) {
    float xv = net[(size_t)k*NPTS + i];
    float xr = fmaxf(xv, 0.f);
    const float* w0r = w0 + k*32;
    const float* wsr = ws + k*32;
#pragma unroll
    for (int j = 0; j < 32; j++) {
      h[j] = fmaf(xr, w0r[j], h[j]);
      y[j] = fmaf(xv, wsr[j], y[j]);
    }
  }
#pragma unroll 16
  for (int k = 0; k < 32; k++) {
    float xv = pooled[(size_t)k*BG + g];
    float xr = fmaxf(xv, 0.f);
    const float* w0r = w0 + (32+k)*32;
    const float* wsr = ws + (32+k)*32;
#pragma unroll
    for (int j = 0; j < 32; j++) {
      h[j] = fmaf(xr, w0r[j], h[j]);
      y[j] = fmaf(xv, wsr[j], y[j]);
    }
  }
#pragma unroll
  for (int j = 0; j < 32; j++) h[j] = fmaxf(h[j], 0.f);
#pragma unroll
  for (int k = 0; k < 32; k++) {
    float hv = h[k];
#pragma unroll
    for (int j = 0; j < 32; j++) y[j] = fmaf(hv, w1[k*32+j], y[j]);
  }
  // fc_c straight from registers
  float c[32];
#pragma unroll
  for (int j = 0; j < 32; j++) c[j] = bc[j];
#pragma unroll
  for (int k = 0; k < 32; k++) {
    float yv = y[k];
#pragma unroll
    for (int j = 0; j < 32; j++) c[j] = fmaf(yv, wc[k*32+j], c[j]);
  }
#pragma unroll
  for (int j = 0; j < 32; j++) net[(size_t)j*NPTS + i] = c[j];
}

// per (ch, cell) max over the cell's contiguous range; cell fastest -> coalesced
__global__ __launch_bounds__(256) void k_pool(
    const float* __restrict__ net, const int* __restrict__ start,
    float* __restrict__ pooled)
{
  int tid = blockIdx.x*256 + threadIdx.x;   // [0, 32*BG)
  int c = tid & (BG-1), ch = tid >> 16;
  int s = start[c], e = start[c+1];
  const float* base = net + (size_t)ch*NPTS;
  float m = -INFINITY;
  for (int k = s; k < e; k++) m = fmaxf(m, base[k]);
  pooled[(size_t)ch*BG + c] = m;
}

// per (ch, cell) mean -> out[b][ch][cell]; empty cells -> 0
__global__ __launch_bounds__(256) void k_mean(
    const float* __restrict__ net, const int* __restrict__ start,
    float* __restrict__ outp)
{
  int tid = blockIdx.x*256 + threadIdx.x;
  int c = tid & (BG-1), ch = tid >> 16;
  int s = start[c], e = start[c+1];
  const float* base = net + (size_t)ch*NPTS;
  float sum = 0.f;
  for (int k = s; k < e; k++) sum += base[k];
  float v = (e > s) ? sum / (float)(e - s) : 0.f;
  int b = c >> 15, cell = c & 32767;
  outp[((size_t)b << 20) + ((size_t)ch << 15) + cell] = v;
}

extern "C" void kernel_launch(void* const* d_in, const int* in_sizes, int n_in,
                              void* d_out, int out_size, void* d_ws, size_t ws_size,
                              hipStream_t stream)
{
  const float* p   = (const float*)d_in[0];
  const float* Wp  = (const float*)d_in[1];
  const float* bp  = (const float*)d_in[2];
  const float* f0w = (const float*)d_in[3];
  const float* f0b = (const float*)d_in[4];
  const float* f1w = (const float*)d_in[5];
  const float* f1b = (const float*)d_in[6];
  const float* scw = (const float*)d_in[7];
  const float* wc  = (const float*)d_in[8];
  const float* bc  = (const float*)d_in[9];
  float* outp = (float*)d_out;

  char* wsb = (char*)d_ws;
  float* net      = (float*)wsb;                         // NPTS*32 f32 = 51.2 MB
  int*   gbuf     = (int*)(net + (size_t)NPTS*32);       // NPTS
  int*   gsort    = gbuf + NPTS;                         // NPTS
  int*   hist     = gsort + NPTS;                        // BG
  int*   start    = hist + BG;                           // BG+1
  int*   cursor   = start + BG + 1;                      // BG
  float* p_sorted = (float*)(cursor + BG);               // NPTS*3
  float* xbuf     = p_sorted + (size_t)NPTS*3;           // NPTS*64 f32 = 102.4 MB
  float* pooled   = xbuf;                                // aliases xbuf (dead after k_res0)

  dim3 blk(256);
  dim3 gpts((NPTS + 255)/256);
  dim3 gcell((BG*32)/256);

  hipMemsetAsync(hist, 0, (size_t)BG*4, stream);
  hipLaunchKernelGGL(k_hist, gpts, blk, 0, stream, p, gbuf, hist);
  hipLaunchKernelGGL(k_scan, dim3(1), dim3(1024), 0, stream, hist, start, cursor);
  hipLaunchKernelGGL(k_scatter, gpts, blk, 0, stream, p, gbuf, cursor, p_sorted, gsort);
  hipLaunchKernelGGL(k_stage0, gpts, blk, 0, stream, p_sorted, Wp, bp, xbuf);
  hipLaunchKernelGGL(k_res0, gpts, blk, 0, stream,
                     xbuf, f0w, f0b, f1w, f1b, scw, net);
  hipLaunchKernelGGL(k_pool, gcell, blk, 0, stream, net, start, pooled);
  hipLaunchKernelGGL(k_stage, gpts, blk, 0, stream, net, gsort, pooled,
                     f0w + 1*2048, f0b + 1*32, f1w + 1*1024, f1b + 1*32, scw + 1*2048);
  hipLaunchKernelGGL(k_pool, gcell, blk, 0, stream, net, start, pooled);
  hipLaunchKernelGGL(k_stage, gpts, blk, 0, stream, net, gsort, pooled,
                     f0w + 2*2048, f0b + 2*32, f1w + 2*1024, f1b + 2*32, scw + 2*2048);
  hipLaunchKernelGGL(k_pool, gcell, blk, 0, stream, net, start, pooled);
  hipLaunchKernelGGL(k_stage, gpts, blk, 0, stream, net, gsort, pooled,
                     f0w + 3*2048, f0b + 3*32, f1w + 3*1024, f1b + 3*32, scw + 3*2048);
  hipLaunchKernelGGL(k_pool, gcell, blk, 0, stream, net, start, pooled);
  hipLaunchKernelGGL(k_final, gpts, blk, 0, stream, net, gsort, pooled,
                     f0w + 4*2048, f0b + 4*32, f1w + 4*1024, f1b + 4*32, scw + 4*2048,
                     wc, bc);
  hipLaunchKernelGGL(k_mean, gcell, blk, 0, stream, net, start, outp);
}

// Round 8
// 455.335 us; speedup vs baseline: 1.7333x; 1.7333x over previous
//
#include <hip/hip_runtime.h>
#include <math.h>

#define TPTS 200000
#define BB 2
#define NPTS (BB*TPTS)
#define GRID3 32768
#define BG 65536   // BB * GRID3

typedef __attribute__((ext_vector_type(8))) __bf16 bf16x8;
typedef __attribute__((ext_vector_type(4))) float f32x4;
typedef unsigned short ushort_t;

#define MFMA16(a,b,c) __builtin_amdgcn_mfma_f32_16x16x32_bf16(a,b,c,0,0,0)

__device__ __forceinline__ void split8(const float* v, bf16x8& hi, bf16x8& lo)
{
#pragma unroll
  for (int j = 0; j < 8; j++) {
    float f = v[j];
    __bf16 h = (__bf16)f;
    hi[j] = h;
    lo[j] = (__bf16)(f - (float)h);   // exact residual, rounded to bf16
  }
}

// cell id: must match reference fp32 arithmetic exactly
__device__ __forceinline__ int cellof(float p0, float p1, float p2, int t)
{
  const float DEN = (float)(1.0 + 0.1 + 1e-3);
  const float HI  = (float)(1.0 - 1e-3);
  float n0 = fminf(fmaxf(p0/DEN + 0.5f, 0.f), HI);
  float n1 = fminf(fmaxf(p1/DEN + 0.5f, 0.f), HI);
  float n2 = fminf(fmaxf(p2/DEN + 0.5f, 0.f), HI);
  int c0 = (int)floorf(n0*32.f), c1 = (int)floorf(n1*32.f), c2 = (int)floorf(n2*32.f);
  return c0 + 32*(c1 + 32*c2) + (t >= TPTS ? GRID3 : 0);
}

__global__ __launch_bounds__(256) void k_hist(
    const float* __restrict__ p, int* __restrict__ gbuf, int* __restrict__ hist)
{
  int t = blockIdx.x*256 + threadIdx.x;
  if (t >= NPTS) return;
  int g = cellof(p[3*t], p[3*t+1], p[3*t+2], t);
  gbuf[t] = g;
  atomicAdd(hist + g, 1);
}

__global__ __launch_bounds__(1024) void k_scan(
    const int* __restrict__ hist, int* __restrict__ start, int* __restrict__ cursor)
{
  __shared__ int sums[1024];
  const int tid = threadIdx.x;
  const int base = tid * (BG/1024);
  int acc = 0;
#pragma unroll 4
  for (int k = 0; k < BG/1024; k++) acc += hist[base+k];
  sums[tid] = acc;
  __syncthreads();
  for (int off = 1; off < 1024; off <<= 1) {
    int v = sums[tid];
    int u = (tid >= off) ? sums[tid-off] : 0;
    __syncthreads();
    sums[tid] = v + u;
    __syncthreads();
  }
  int run = (tid > 0) ? sums[tid-1] : 0;
#pragma unroll 4
  for (int k = 0; k < BG/1024; k++) {
    start[base+k] = run; cursor[base+k] = run;
    run += hist[base+k];
  }
  if (tid == 1023) start[BG] = sums[1023];
}

__global__ __launch_bounds__(256) void k_scatter(
    const float* __restrict__ p, const int* __restrict__ gbuf,
    int* __restrict__ cursor, float* __restrict__ p_sorted, int* __restrict__ gsort)
{
  int t = blockIdx.x*256 + threadIdx.x;
  if (t >= NPTS) return;
  int g = gbuf[t];
  int slot = atomicAdd(cursor + g, 1);
  gsort[slot] = g;
  p_sorted[3*slot]   = p[3*t];
  p_sorted[3*slot+1] = p[3*t+1];
  p_sorted[3*slot+2] = p[3*t+2];
}

// pack weights into MFMA B-fragment order (bf16 hi/lo), once.
// frag layout: value(lane l, elem j) = W[k = c*32 + (l>>4)*8 + j][n = t*16 + (l&15)]
// frag ids: stage s base = s*20; w0: (c*2+t)*2+e; ws: 8+...; w1: 16 + t*2+e; wc at 100.
__global__ void k_pack(
    const float* __restrict__ f0w, const float* __restrict__ scw,
    const float* __restrict__ f1w, const float* __restrict__ wc,
    ushort_t* __restrict__ wpack)
{
  int f = blockIdx.x, l = threadIdx.x;
  const float* W; int c, t, e;
  if (f < 100) {
    int s = f / 20, r = f % 20;
    if (r < 8)       { W = f0w + s*2048; c = r>>2;        t = (r>>1)&1; e = r&1; }
    else if (r < 16) { int q = r-8;  W = scw + s*2048; c = q>>2; t = (q>>1)&1; e = q&1; }
    else             { int q = r-16; W = f1w + s*1024; c = 0;    t = q>>1;     e = q&1; }
  } else { int q = f-100; W = wc; c = 0; t = q>>1; e = q&1; }
#pragma unroll
  for (int j = 0; j < 8; j++) {
    int k = c*32 + (l>>4)*8 + j, n = t*16 + (l&15);
    float v = W[k*32 + n];
    __bf16 h = (__bf16)v;
    __bf16 out = (e == 0) ? h : (__bf16)(v - (float)h);
    union { __bf16 b; ushort_t u; } cv; cv.b = out;
    wpack[((size_t)f*64 + l)*8 + j] = cv.u;
  }
}

// posenc + fc_pos -> xbuf AoS [pt][64]
__global__ __launch_bounds__(256) void k_stage0(
    const float* __restrict__ ps,
    const float* __restrict__ Wp, const float* __restrict__ bp,
    float* __restrict__ xbuf)
{
  int i = blockIdx.x*256 + threadIdx.x;
  if (i >= NPTS) return;
  float p0 = ps[3*i], p1 = ps[3*i+1], p2 = ps[3*i+2];

  float x[64];
#pragma unroll
  for (int j = 0; j < 64; j++) x[j] = bp[j];

  float u0 = 2.f*p0 - 1.f, u1 = 2.f*p1 - 1.f, u2 = 2.f*p2 - 1.f;
  const float PIF = 3.14159265358979323846f;
#pragma unroll 1
  for (int l = 0; l < 10; l++) {
    float uu[3] = {u0, u1, u2};
#pragma unroll
    for (int d = 0; d < 3; d++) {
      float r = uu[d] - 2.f*rintf(0.5f*uu[d]);   // exact mod-2 reduction
      float s, c;
      __sincosf(PIF*r, &s, &c);
      const float* wsr = Wp + (l*6 + d)*64;
      const float* wcr = Wp + (l*6 + 3 + d)*64;
#pragma unroll
      for (int j = 0; j < 64; j++) x[j] = fmaf(s, wsr[j], fmaf(c, wcr[j], x[j]));
    }
    u0 *= 2.f; u1 *= 2.f; u2 *= 2.f;
  }
#pragma unroll
  for (int jj = 0; jj < 16; jj++)
    *(f32x4*)(xbuf + (size_t)i*64 + jj*4) =
      (f32x4){x[4*jj], x[4*jj+1], x[4*jj+2], x[4*jj+3]};
}

// resblock0 via MFMA: x[64] from xbuf AoS -> net AoS [pt][32]
__global__ __launch_bounds__(256) void k_res0_m(
    const float* __restrict__ xbuf,
    const ushort_t* __restrict__ wp,
    const float* __restrict__ b0, const float* __restrict__ b1,
    float* __restrict__ net)
{
  __shared__ float hbuf[4][16*36];
  int wave = threadIdx.x >> 6, lane = threadIdx.x & 63;
  int m = lane & 15, q = lane >> 4;
  int pbase = (blockIdx.x*4 + wave)*16;
  int pt = pbase + m;

  bf16x8 w0f[2][2][2], wsf[2][2][2], w1f[2][2];
#pragma unroll
  for (int c = 0; c < 2; c++)
#pragma unroll
    for (int t = 0; t < 2; t++)
#pragma unroll
      for (int e = 0; e < 2; e++) {
        w0f[c][t][e] = *(const bf16x8*)(wp + ((size_t)(((c*2+t)*2+e)    )*64 + lane)*8);
        wsf[c][t][e] = *(const bf16x8*)(wp + ((size_t)(((c*2+t)*2+e) + 8)*64 + lane)*8);
      }
#pragma unroll
  for (int t = 0; t < 2; t++)
#pragma unroll
    for (int e = 0; e < 2; e++)
      w1f[t][e] = *(const bf16x8*)(wp + ((size_t)(16 + t*2 + e)*64 + lane)*8);

  float xv[2][8];
#pragma unroll
  for (int c = 0; c < 2; c++) {
    const float* a = xbuf + (size_t)pt*64 + c*32 + q*8;
    *(f32x4*)&xv[c][0] = *(const f32x4*)a;
    *(f32x4*)&xv[c][4] = *(const f32x4*)(a+4);
  }

  bf16x8 axh[2], axl[2], arh[2], arl[2];
#pragma unroll
  for (int c = 0; c < 2; c++) {
    float r[8];
#pragma unroll
    for (int j = 0; j < 8; j++) r[j] = fmaxf(xv[c][j], 0.f);
    split8(xv[c], axh[c], axl[c]);
    split8(r,     arh[c], arl[c]);
  }

  f32x4 hacc[2], yacc[2];
#pragma unroll
  for (int t = 0; t < 2; t++) {
    float bb0 = b0[m + 16*t], bb1 = b1[m + 16*t];
    hacc[t] = (f32x4){bb0,bb0,bb0,bb0};
    yacc[t] = (f32x4){bb1,bb1,bb1,bb1};
  }

#pragma unroll
  for (int c = 0; c < 2; c++)
#pragma unroll
    for (int t = 0; t < 2; t++) {
      hacc[t] = MFMA16(arh[c], w0f[c][t][0], hacc[t]);
      hacc[t] = MFMA16(arl[c], w0f[c][t][0], hacc[t]);
      hacc[t] = MFMA16(arh[c], w0f[c][t][1], hacc[t]);
      yacc[t] = MFMA16(axh[c], wsf[c][t][0], yacc[t]);
      yacc[t] = MFMA16(axl[c], wsf[c][t][0], yacc[t]);
      yacc[t] = MFMA16(axh[c], wsf[c][t][1], yacc[t]);
    }

  float* hb = hbuf[wave];
#pragma unroll
  for (int t = 0; t < 2; t++)
#pragma unroll
    for (int r = 0; r < 4; r++)
      hb[(q*4+r)*36 + m + 16*t] = fmaxf(hacc[t][r], 0.f);
  __syncthreads();
  float hv[8];
#pragma unroll
  for (int j = 0; j < 8; j++) hv[j] = hb[m*36 + q*8 + j];
  bf16x8 hh, hl; split8(hv, hh, hl);
#pragma unroll
  for (int t = 0; t < 2; t++) {
    yacc[t] = MFMA16(hh, w1f[t][0], yacc[t]);
    yacc[t] = MFMA16(hl, w1f[t][0], yacc[t]);
    yacc[t] = MFMA16(hh, w1f[t][1], yacc[t]);
  }

#pragma unroll
  for (int t = 0; t < 2; t++)
#pragma unroll
    for (int r = 0; r < 4; r++)
      net[(size_t)(pbase + q*4 + r)*32 + m + 16*t] = yacc[t][r];
}

// middle stages via MFMA: x = [net[pt], pooled[g]] -> net
__global__ __launch_bounds__(256) void k_stage_m(
    float* __restrict__ net, const int* __restrict__ gsort,
    const float* __restrict__ pooled,
    const ushort_t* __restrict__ wp,
    const float* __restrict__ b0, const float* __restrict__ b1)
{
  __shared__ float hbuf[4][16*36];
  int wave = threadIdx.x >> 6, lane = threadIdx.x & 63;
  int m = lane & 15, q = lane >> 4;
  int pbase = (blockIdx.x*4 + wave)*16;
  int pt = pbase + m;

  bf16x8 w0f[2][2][2], wsf[2][2][2], w1f[2][2];
#pragma unroll
  for (int c = 0; c < 2; c++)
#pragma unroll
    for (int t = 0; t < 2; t++)
#pragma unroll
      for (int e = 0; e < 2; e++) {
        w0f[c][t][e] = *(const bf16x8*)(wp + ((size_t)(((c*2+t)*2+e)    )*64 + lane)*8);
        wsf[c][t][e] = *(const bf16x8*)(wp + ((size_t)(((c*2+t)*2+e) + 8)*64 + lane)*8);
      }
#pragma unroll
  for (int t = 0; t < 2; t++)
#pragma unroll
    for (int e = 0; e < 2; e++)
      w1f[t][e] = *(const bf16x8*)(wp + ((size_t)(16 + t*2 + e)*64 + lane)*8);

  float xv[2][8];
  {
    const float* a = net + (size_t)pt*32 + q*8;
    *(f32x4*)&xv[0][0] = *(const f32x4*)a;
    *(f32x4*)&xv[0][4] = *(const f32x4*)(a+4);
    int g = gsort[pt];
    const float* b = pooled + (size_t)g*32 + q*8;
    *(f32x4*)&xv[1][0] = *(const f32x4*)b;
    *(f32x4*)&xv[1][4] = *(const f32x4*)(b+4);
  }

  bf16x8 axh[2], axl[2], arh[2], arl[2];
#pragma unroll
  for (int c = 0; c < 2; c++) {
    float r[8];
#pragma unroll
    for (int j = 0; j < 8; j++) r[j] = fmaxf(xv[c][j], 0.f);
    split8(xv[c], axh[c], axl[c]);
    split8(r,     arh[c], arl[c]);
  }

  f32x4 hacc[2], yacc[2];
#pragma unroll
  for (int t = 0; t < 2; t++) {
    float bb0 = b0[m + 16*t], bb1 = b1[m + 16*t];
    hacc[t] = (f32x4){bb0,bb0,bb0,bb0};
    yacc[t] = (f32x4){bb1,bb1,bb1,bb1};
  }

#pragma unroll
  for (int c = 0; c < 2; c++)
#pragma unroll
    for (int t = 0; t < 2; t++) {
      hacc[t] = MFMA16(arh[c], w0f[c][t][0], hacc[t]);
      hacc[t] = MFMA16(arl[c], w0f[c][t][0], hacc[t]);
      hacc[t] = MFMA16(arh[c], w0f[c][t][1], hacc[t]);
      yacc[t] = MFMA16(axh[c], wsf[c][t][0], yacc[t]);
      yacc[t] = MFMA16(axl[c], wsf[c][t][0], yacc[t]);
      yacc[t] = MFMA16(axh[c], wsf[c][t][1], yacc[t]);
    }

  float* hb = hbuf[wave];
#pragma unroll
  for (int t = 0; t < 2; t++)
#pragma unroll
    for (int r = 0; r < 4; r++)
      hb[(q*4+r)*36 + m + 16*t] = fmaxf(hacc[t][r], 0.f);
  __syncthreads();
  float hv[8];
#pragma unroll
  for (int j = 0; j < 8; j++) hv[j] = hb[m*36 + q*8 + j];
  bf16x8 hh, hl; split8(hv, hh, hl);
#pragma unroll
  for (int t = 0; t < 2; t++) {
    yacc[t] = MFMA16(hh, w1f[t][0], yacc[t]);
    yacc[t] = MFMA16(hl, w1f[t][0], yacc[t]);
    yacc[t] = MFMA16(hh, w1f[t][1], yacc[t]);
  }

#pragma unroll
  for (int t = 0; t < 2; t++)
#pragma unroll
    for (int r = 0; r < 4; r++)
      net[(size_t)(pbase + q*4 + r)*32 + m + 16*t] = yacc[t][r];
}

// final stage + fc_c via MFMA
__global__ __launch_bounds__(256) void k_final_m(
    float* __restrict__ net, const int* __restrict__ gsort,
    const float* __restrict__ pooled,
    const ushort_t* __restrict__ wp, const ushort_t* __restrict__ wpc,
    const float* __restrict__ b0, const float* __restrict__ b1,
    const float* __restrict__ bc)
{
  __shared__ float hbuf[4][16*36];
  __shared__ float ybuf[4][16*36];
  int wave = threadIdx.x >> 6, lane = threadIdx.x & 63;
  int m = lane & 15, q = lane >> 4;
  int pbase = (blockIdx.x*4 + wave)*16;
  int pt = pbase + m;

  bf16x8 w0f[2][2][2], wsf[2][2][2], w1f[2][2], wcf[2][2];
#pragma unroll
  for (int c = 0; c < 2; c++)
#pragma unroll
    for (int t = 0; t < 2; t++)
#pragma unroll
      for (int e = 0; e < 2; e++) {
        w0f[c][t][e] = *(const bf16x8*)(wp + ((size_t)(((c*2+t)*2+e)    )*64 + lane)*8);
        wsf[c][t][e] = *(const bf16x8*)(wp + ((size_t)(((c*2+t)*2+e) + 8)*64 + lane)*8);
      }
#pragma unroll
  for (int t = 0; t < 2; t++)
#pragma unroll
    for (int e = 0; e < 2; e++) {
      w1f[t][e] = *(const bf16x8*)(wp  + ((size_t)(16 + t*2 + e)*64 + lane)*8);
      wcf[t][e] = *(const bf16x8*)(wpc + ((size_t)(     t*2 + e)*64 + lane)*8);
    }

  float xv[2][8];
  {
    const float* a = net + (size_t)pt*32 + q*8;
    *(f32x4*)&xv[0][0] = *(const f32x4*)a;
    *(f32x4*)&xv[0][4] = *(const f32x4*)(a+4);
    int g = gsort[pt];
    const float* b = pooled + (size_t)g*32 + q*8;
    *(f32x4*)&xv[1][0] = *(const f32x4*)b;
    *(f32x4*)&xv[1][4] = *(const f32x4*)(b+4);
  }

  bf16x8 axh[2], axl[2], arh[2], arl[2];
#pragma unroll
  for (int c = 0; c < 2; c++) {
    float r[8];
#pragma unroll
    for (int j = 0; j < 8; j++) r[j] = fmaxf(xv[c][j], 0.f);
    split8(xv[c], axh[c], axl[c]);
    split8(r,     arh[c], arl[c]);
  }

  f32x4 hacc[2], yacc[2];
#pragma unroll
  for (int t = 0; t < 2; t++) {
    float bb0 = b0[m + 16*t], bb1 = b1[m + 16*t];
    hacc[t] = (f32x4){bb0,bb0,bb0,bb0};
    yacc[t] = (f32x4){bb1,bb1,bb1,bb1};
  }

#pragma unroll
  for (int c = 0; c < 2; c++)
#pragma unroll
    for (int t = 0; t < 2; t++) {
      hacc[t] = MFMA16(arh[c], w0f[c][t][0], hacc[t]);
      hacc[t] = MFMA16(arl[c], w0f[c][t][0], hacc[t]);
      hacc[t] = MFMA16(arh[c], w0f[c][t][1], hacc[t]);
      yacc[t] = MFMA16(axh[c], wsf[c][t][0], yacc[t]);
      yacc[t] = MFMA16(axl[c], wsf[c][t][0], yacc[t]);
      yacc[t] = MFMA16(axh[c], wsf[c][t][1], yacc[t]);
    }

  float* hb = hbuf[wave];
#pragma unroll
  for (int t = 0; t < 2; t++)
#pragma unroll
    for (int r = 0; r < 4; r++)
      hb[(q*4+r)*36 + m + 16*t] = fmaxf(hacc[t][r], 0.f);
  __syncthreads();
  float hv[8];
#pragma unroll
  for (int j = 0; j < 8; j++) hv[j] = hb[m*36 + q*8 + j];
  bf16x8 hh, hl; split8(hv, hh, hl);
#pragma unroll
  for (int t = 0; t < 2; t++) {
    yacc[t] = MFMA16(hh, w1f[t][0], yacc[t]);
    yacc[t] = MFMA16(hl, w1f[t][0], yacc[t]);
    yacc[t] = MFMA16(hh, w1f[t][1], yacc[t]);
  }

  // y -> A-layout via LDS for fc_c
  float* yb = ybuf[wave];
#pragma unroll
  for (int t = 0; t < 2; t++)
#pragma unroll
    for (int r = 0; r < 4; r++)
      yb[(q*4+r)*36 + m + 16*t] = yacc[t][r];
  __syncthreads();
  float yv[8];
#pragma unroll
  for (int j = 0; j < 8; j++) yv[j] = yb[m*36 + q*8 + j];
  bf16x8 yh, yl; split8(yv, yh, yl);

  f32x4 cacc[2];
#pragma unroll
  for (int t = 0; t < 2; t++) {
    float bb = bc[m + 16*t];
    cacc[t] = (f32x4){bb,bb,bb,bb};
    cacc[t] = MFMA16(yh, wcf[t][0], cacc[t]);
    cacc[t] = MFMA16(yl, wcf[t][0], cacc[t]);
    cacc[t] = MFMA16(yh, wcf[t][1], cacc[t]);
  }

#pragma unroll
  for (int t = 0; t < 2; t++)
#pragma unroll
    for (int r = 0; r < 4; r++)
      net[(size_t)(pbase + q*4 + r)*32 + m + 16*t] = cacc[t][r];
}

// AoS pool: 8 threads per cell, each float4 of 4 channels
__global__ __launch_bounds__(256) void k_pool(
    const float* __restrict__ net, const int* __restrict__ start,
    float* __restrict__ pooled)
{
  int tid = blockIdx.x*256 + threadIdx.x;   // [0, BG*8)
  int c = tid >> 3, sub = tid & 7;
  int s = start[c], e = start[c+1];
  f32x4 mx = (f32x4){-INFINITY,-INFINITY,-INFINITY,-INFINITY};
  for (int k = s; k < e; k++) {
    f32x4 v = *(const f32x4*)(net + (size_t)k*32 + sub*4);
    mx.x = fmaxf(mx.x, v.x); mx.y = fmaxf(mx.y, v.y);
    mx.z = fmaxf(mx.z, v.z); mx.w = fmaxf(mx.w, v.w);
  }
  *(f32x4*)(pooled + (size_t)c*32 + sub*4) = mx;
}

// AoS mean -> out[b][ch][cell]; empty cells -> 0
__global__ __launch_bounds__(256) void k_mean(
    const float* __restrict__ net, const int* __restrict__ start,
    float* __restrict__ outp)
{
  int tid = blockIdx.x*256 + threadIdx.x;   // [0, BG*8)
  int c = tid >> 3, sub = tid & 7;
  int s = start[c], e = start[c+1];
  f32x4 sum = (f32x4){0.f,0.f,0.f,0.f};
  for (int k = s; k < e; k++) {
    f32x4 v = *(const f32x4*)(net + (size_t)k*32 + sub*4);
    sum.x += v.x; sum.y += v.y; sum.z += v.z; sum.w += v.w;
  }
  float inv = (e > s) ? 1.f/(float)(e - s) : 0.f;
  int b = c >> 15, cell = c & 32767;
  size_t ob = ((size_t)b << 20) + cell;
#pragma unroll
  for (int jj = 0; jj < 4; jj++) {
    int ch = sub*4 + jj;
    float v = ((const float*)&sum)[jj] * inv;
    outp[ob + ((size_t)ch << 15)] = v;
  }
}

extern "C" void kernel_launch(void* const* d_in, const int* in_sizes, int n_in,
                              void* d_out, int out_size, void* d_ws, size_t ws_size,
                              hipStream_t stream)
{
  const float* p   = (const float*)d_in[0];
  const float* Wp  = (const float*)d_in[1];
  const float* bp  = (const float*)d_in[2];
  const float* f0w = (const float*)d_in[3];
  const float* f0b = (const float*)d_in[4];
  const float* f1w = (const float*)d_in[5];
  const float* f1b = (const float*)d_in[6];
  const float* scw = (const float*)d_in[7];
  const float* wc  = (const float*)d_in[8];
  const float* bc  = (const float*)d_in[9];
  float* outp = (float*)d_out;

  char* wsb = (char*)d_ws;
  float*    net      = (float*)wsb;                       // NPTS*32 f32 = 51.2 MB
  int*      gbuf     = (int*)(net + (size_t)NPTS*32);     // NPTS
  int*      gsort    = gbuf + NPTS;                       // NPTS
  int*      hist     = gsort + NPTS;                      // BG
  int*      start    = hist + BG;                         // BG+1
  int*      cursor   = start + BG + 1;                    // BG
  ushort_t* wpack    = (ushort_t*)(cursor + BG);          // 104*512 ushort = 104 KB
  float*    p_sorted = (float*)(wpack + (size_t)104*512); // NPTS*3
  float*    xbuf     = p_sorted + (size_t)NPTS*3;         // NPTS*64 f32 = 102.4 MB
  float*    pooled   = xbuf;                              // aliases xbuf (dead after res0)

  dim3 blk(256);
  dim3 gpts((NPTS + 255)/256);
  dim3 gmfma(NPTS/64);          // 6250 blocks, 4 waves x 16 pts
  dim3 gcell((BG*8)/256);       // 2048 blocks

  hipMemsetAsync(hist, 0, (size_t)BG*4, stream);
  hipLaunchKernelGGL(k_hist, gpts, blk, 0, stream, p, gbuf, hist);
  hipLaunchKernelGGL(k_scan, dim3(1), dim3(1024), 0, stream, hist, start, cursor);
  hipLaunchKernelGGL(k_scatter, gpts, blk, 0, stream, p, gbuf, cursor, p_sorted, gsort);
  hipLaunchKernelGGL(k_pack, dim3(104), dim3(64), 0, stream, f0w, scw, f1w, wc, wpack);
  hipLaunchKernelGGL(k_stage0, gpts, blk, 0, stream, p_sorted, Wp, bp, xbuf);
  hipLaunchKernelGGL(k_res0_m, gmfma, blk, 0, stream,
                     xbuf, wpack + (size_t)0*20*512, f0b + 0*32, f1b + 0*32, net);
  hipLaunchKernelGGL(k_pool, gcell, blk, 0, stream, net, start, pooled);
  hipLaunchKernelGGL(k_stage_m, gmfma, blk, 0, stream, net, gsort, pooled,
                     wpack + (size_t)1*20*512, f0b + 1*32, f1b + 1*32);
  hipLaunchKernelGGL(k_pool, gcell, blk, 0, stream, net, start, pooled);
  hipLaunchKernelGGL(k_stage_m, gmfma, blk, 0, stream, net, gsort, pooled,
                     wpack + (size_t)2*20*512, f0b + 2*32, f1b + 2*32);
  hipLaunchKernelGGL(k_pool, gcell, blk, 0, stream, net, start, pooled);
  hipLaunchKernelGGL(k_stage_m, gmfma, blk, 0, stream, net, gsort, pooled,
                     wpack + (size_t)3*20*512, f0b + 3*32, f1b + 3*32);
  hipLaunchKernelGGL(k_pool, gcell, blk, 0, stream, net, start, pooled);
  hipLaunchKernelGGL(k_final_m, gmfma, blk, 0, stream, net, gsort, pooled,
                     wpack + (size_t)4*20*512, wpack + (size_t)100*512,
                     f0b + 4*32, f1b + 4*32, bc);
  hipLaunchKernelGGL(k_mean, gcell, blk, 0, stream, net, start, outp);
}

// Round 9
// 428.137 us; speedup vs baseline: 1.8434x; 1.0635x over previous
//
#include <hip/hip_runtime.h>
#include <math.h>

#define TPTS 200000
#define BB 2
#define NPTS (BB*TPTS)
#define GRID3 32768
#define BG 65536   // BB * GRID3

typedef __attribute__((ext_vector_type(8))) __bf16 bf16x8;
typedef __attribute__((ext_vector_type(4))) float f32x4;
typedef unsigned short ushort_t;

#define MFMA16(a,b,c) __builtin_amdgcn_mfma_f32_16x16x32_bf16(a,b,c,0,0,0)

__device__ __forceinline__ void split8(const float* v, bf16x8& hi, bf16x8& lo)
{
#pragma unroll
  for (int j = 0; j < 8; j++) {
    float f = v[j];
    __bf16 h = (__bf16)f;
    hi[j] = h;
    lo[j] = (__bf16)(f - (float)h);   // exact residual, rounded to bf16
  }
}

// cell id: must match reference fp32 arithmetic exactly
__device__ __forceinline__ int cellof(float p0, float p1, float p2, int t)
{
  const float DEN = (float)(1.0 + 0.1 + 1e-3);
  const float HI  = (float)(1.0 - 1e-3);
  float n0 = fminf(fmaxf(p0/DEN + 0.5f, 0.f), HI);
  float n1 = fminf(fmaxf(p1/DEN + 0.5f, 0.f), HI);
  float n2 = fminf(fmaxf(p2/DEN + 0.5f, 0.f), HI);
  int c0 = (int)floorf(n0*32.f), c1 = (int)floorf(n1*32.f), c2 = (int)floorf(n2*32.f);
  return c0 + 32*(c1 + 32*c2) + (t >= TPTS ? GRID3 : 0);
}

__global__ __launch_bounds__(256) void k_hist(
    const float* __restrict__ p, int* __restrict__ gbuf, int* __restrict__ hist)
{
  int t = blockIdx.x*256 + threadIdx.x;
  if (t >= NPTS) return;
  int g = cellof(p[3*t], p[3*t+1], p[3*t+2], t);
  gbuf[t] = g;
  atomicAdd(hist + g, 1);
}

__global__ __launch_bounds__(1024) void k_scan(
    const int* __restrict__ hist, int* __restrict__ start, int* __restrict__ cursor)
{
  __shared__ int sums[1024];
  const int tid = threadIdx.x;
  const int base = tid * (BG/1024);
  int acc = 0;
#pragma unroll 4
  for (int k = 0; k < BG/1024; k++) acc += hist[base+k];
  sums[tid] = acc;
  __syncthreads();
  for (int off = 1; off < 1024; off <<= 1) {
    int v = sums[tid];
    int u = (tid >= off) ? sums[tid-off] : 0;
    __syncthreads();
    sums[tid] = v + u;
    __syncthreads();
  }
  int run = (tid > 0) ? sums[tid-1] : 0;
#pragma unroll 4
  for (int k = 0; k < BG/1024; k++) {
    start[base+k] = run; cursor[base+k] = run;
    run += hist[base+k];
  }
  if (tid == 1023) start[BG] = sums[1023];
}

__global__ __launch_bounds__(256) void k_scatter(
    const float* __restrict__ p, const int* __restrict__ gbuf,
    int* __restrict__ cursor, float* __restrict__ p_sorted, int* __restrict__ gsort)
{
  int t = blockIdx.x*256 + threadIdx.x;
  if (t >= NPTS) return;
  int g = gbuf[t];
  int slot = atomicAdd(cursor + g, 1);
  gsort[slot] = g;
  p_sorted[3*slot]   = p[3*t];
  p_sorted[3*slot+1] = p[3*t+1];
  p_sorted[3*slot+2] = p[3*t+2];
}

// pack weights into MFMA B-fragment order (bf16 hi/lo), once.
__global__ void k_pack(
    const float* __restrict__ f0w, const float* __restrict__ scw,
    const float* __restrict__ f1w, const float* __restrict__ wc,
    ushort_t* __restrict__ wpack)
{
  int f = blockIdx.x, l = threadIdx.x;
  const float* W; int c, t, e;
  if (f < 100) {
    int s = f / 20, r = f % 20;
    if (r < 8)       { W = f0w + s*2048; c = r>>2;        t = (r>>1)&1; e = r&1; }
    else if (r < 16) { int q = r-8;  W = scw + s*2048; c = q>>2; t = (q>>1)&1; e = q&1; }
    else             { int q = r-16; W = f1w + s*1024; c = 0;    t = q>>1;     e = q&1; }
  } else { int q = f-100; W = wc; c = 0; t = q>>1; e = q&1; }
#pragma unroll
  for (int j = 0; j < 8; j++) {
    int k = c*32 + (l>>4)*8 + j, n = t*16 + (l&15);
    float v = W[k*32 + n];
    __bf16 h = (__bf16)v;
    __bf16 out = (e == 0) ? h : (__bf16)(v - (float)h);
    union { __bf16 b; ushort_t u; } cv; cv.b = out;
    wpack[((size_t)f*64 + l)*8 + l*0 + j] = cv.u;
  }
}

// FUSED: posenc + fc_pos computed per-lane directly in A-fragment layout,
// then resblock0 via MFMA -> net AoS [pt][32]. No xbuf.
__global__ __launch_bounds__(256) void k_fused0(
    const float* __restrict__ ps,
    const float* __restrict__ Wp, const float* __restrict__ bp,
    const ushort_t* __restrict__ wp,
    const float* __restrict__ b0, const float* __restrict__ b1,
    float* __restrict__ net)
{
  __shared__ __align__(16) float s_Wp[3840];
  __shared__ float s_bp[64];
  __shared__ float hbuf[4][16*36];
  {
    int t = threadIdx.x;
    for (int idx = t; idx < 3840; idx += 256) s_Wp[idx] = Wp[idx];
    if (t < 64) s_bp[t] = bp[t];
  }
  __syncthreads();

  int wave = threadIdx.x >> 6, lane = threadIdx.x & 63;
  int m = lane & 15, q = lane >> 4;
  int pbase = (blockIdx.x*4 + wave)*16;
  int pt = pbase + m;

  // weight fragments (loaded once, reused; coalesced 16B loads)
  bf16x8 w0f[2][2][2], wsf[2][2][2], w1f[2][2];
#pragma unroll
  for (int c = 0; c < 2; c++)
#pragma unroll
    for (int t = 0; t < 2; t++)
#pragma unroll
      for (int e = 0; e < 2; e++) {
        w0f[c][t][e] = *(const bf16x8*)(wp + ((size_t)(((c*2+t)*2+e)    )*64 + lane)*8);
        wsf[c][t][e] = *(const bf16x8*)(wp + ((size_t)(((c*2+t)*2+e) + 8)*64 + lane)*8);
      }
#pragma unroll
  for (int t = 0; t < 2; t++)
#pragma unroll
    for (int e = 0; e < 2; e++)
      w1f[t][e] = *(const bf16x8*)(wp + ((size_t)(16 + t*2 + e)*64 + lane)*8);

  // posenc + fc_pos for MY 16 channels of point pt
  // xv[c][jj] = channel c*32 + q*8 + jj
  float p0 = ps[3*pt], p1 = ps[3*pt+1], p2 = ps[3*pt+2];
  float xv[2][8];
#pragma unroll
  for (int c = 0; c < 2; c++)
#pragma unroll
    for (int jj = 0; jj < 8; jj++) xv[c][jj] = s_bp[c*32 + q*8 + jj];

  float u[3] = {2.f*p0 - 1.f, 2.f*p1 - 1.f, 2.f*p2 - 1.f};
  const float PIF = 3.14159265358979323846f;
#pragma unroll 1
  for (int l = 0; l < 10; l++) {
#pragma unroll
    for (int d = 0; d < 3; d++) {
      float r = u[d] - 2.f*rintf(0.5f*u[d]);   // exact mod-2 reduction
      float s, c;
      __sincosf(PIF*r, &s, &c);
      const float* wsr = s_Wp + (l*6 + d)*64 + q*8;
      const float* wcr = s_Wp + (l*6 + 3 + d)*64 + q*8;
#pragma unroll
      for (int c2 = 0; c2 < 2; c2++)
#pragma unroll
        for (int jj = 0; jj < 8; jj++)
          xv[c2][jj] = fmaf(s, wsr[c2*32 + jj], fmaf(c, wcr[c2*32 + jj], xv[c2][jj]));
      u[d] *= 2.f;
    }
  }

  // resblock0 via MFMA
  bf16x8 axh[2], axl[2], arh[2], arl[2];
#pragma unroll
  for (int c = 0; c < 2; c++) {
    float r[8];
#pragma unroll
    for (int j = 0; j < 8; j++) r[j] = fmaxf(xv[c][j], 0.f);
    split8(xv[c], axh[c], axl[c]);
    split8(r,     arh[c], arl[c]);
  }

  f32x4 hacc[2], yacc[2];
#pragma unroll
  for (int t = 0; t < 2; t++) {
    float bb0 = b0[m + 16*t], bb1 = b1[m + 16*t];
    hacc[t] = (f32x4){bb0,bb0,bb0,bb0};
    yacc[t] = (f32x4){bb1,bb1,bb1,bb1};
  }

#pragma unroll
  for (int c = 0; c < 2; c++)
#pragma unroll
    for (int t = 0; t < 2; t++) {
      hacc[t] = MFMA16(arh[c], w0f[c][t][0], hacc[t]);
      hacc[t] = MFMA16(arl[c], w0f[c][t][0], hacc[t]);
      hacc[t] = MFMA16(arh[c], w0f[c][t][1], hacc[t]);
      yacc[t] = MFMA16(axh[c], wsf[c][t][0], yacc[t]);
      yacc[t] = MFMA16(axl[c], wsf[c][t][0], yacc[t]);
      yacc[t] = MFMA16(axh[c], wsf[c][t][1], yacc[t]);
    }

  float* hb = hbuf[wave];
#pragma unroll
  for (int t = 0; t < 2; t++)
#pragma unroll
    for (int r = 0; r < 4; r++)
      hb[(q*4+r)*36 + m + 16*t] = fmaxf(hacc[t][r], 0.f);
  __syncthreads();
  float hv[8];
#pragma unroll
  for (int j = 0; j < 8; j++) hv[j] = hb[m*36 + q*8 + j];
  bf16x8 hh, hl; split8(hv, hh, hl);
#pragma unroll
  for (int t = 0; t < 2; t++) {
    yacc[t] = MFMA16(hh, w1f[t][0], yacc[t]);
    yacc[t] = MFMA16(hl, w1f[t][0], yacc[t]);
    yacc[t] = MFMA16(hh, w1f[t][1], yacc[t]);
  }

#pragma unroll
  for (int t = 0; t < 2; t++)
#pragma unroll
    for (int r = 0; r < 4; r++)
      net[(size_t)(pbase + q*4 + r)*32 + m + 16*t] = yacc[t][r];
}

// middle stages via MFMA: x = [net[pt], pooled[g]] -> net
__global__ __launch_bounds__(256) void k_stage_m(
    float* __restrict__ net, const int* __restrict__ gsort,
    const float* __restrict__ pooled,
    const ushort_t* __restrict__ wp,
    const float* __restrict__ b0, const float* __restrict__ b1)
{
  __shared__ float hbuf[4][16*36];
  int wave = threadIdx.x >> 6, lane = threadIdx.x & 63;
  int m = lane & 15, q = lane >> 4;
  int pbase = (blockIdx.x*4 + wave)*16;
  int pt = pbase + m;

  bf16x8 w0f[2][2][2], wsf[2][2][2], w1f[2][2];
#pragma unroll
  for (int c = 0; c < 2; c++)
#pragma unroll
    for (int t = 0; t < 2; t++)
#pragma unroll
      for (int e = 0; e < 2; e++) {
        w0f[c][t][e] = *(const bf16x8*)(wp + ((size_t)(((c*2+t)*2+e)    )*64 + lane)*8);
        wsf[c][t][e] = *(const bf16x8*)(wp + ((size_t)(((c*2+t)*2+e) + 8)*64 + lane)*8);
      }
#pragma unroll
  for (int t = 0; t < 2; t++)
#pragma unroll
    for (int e = 0; e < 2; e++)
      w1f[t][e] = *(const bf16x8*)(wp + ((size_t)(16 + t*2 + e)*64 + lane)*8);

  float xv[2][8];
  {
    const float* a = net + (size_t)pt*32 + q*8;
    *(f32x4*)&xv[0][0] = *(const f32x4*)a;
    *(f32x4*)&xv[0][4] = *(const f32x4*)(a+4);
    int g = gsort[pt];
    const float* b = pooled + (size_t)g*32 + q*8;
    *(f32x4*)&xv[1][0] = *(const f32x4*)b;
    *(f32x4*)&xv[1][4] = *(const f32x4*)(b+4);
  }

  bf16x8 axh[2], axl[2], arh[2], arl[2];
#pragma unroll
  for (int c = 0; c < 2; c++) {
    float r[8];
#pragma unroll
    for (int j = 0; j < 8; j++) r[j] = fmaxf(xv[c][j], 0.f);
    split8(xv[c], axh[c], axl[c]);
    split8(r,     arh[c], arl[c]);
  }

  f32x4 hacc[2], yacc[2];
#pragma unroll
  for (int t = 0; t < 2; t++) {
    float bb0 = b0[m + 16*t], bb1 = b1[m + 16*t];
    hacc[t] = (f32x4){bb0,bb0,bb0,bb0};
    yacc[t] = (f32x4){bb1,bb1,bb1,bb1};
  }

#pragma unroll
  for (int c = 0; c < 2; c++)
#pragma unroll
    for (int t = 0; t < 2; t++) {
      hacc[t] = MFMA16(arh[c], w0f[c][t][0], hacc[t]);
      hacc[t] = MFMA16(arl[c], w0f[c][t][0], hacc[t]);
      hacc[t] = MFMA16(arh[c], w0f[c][t][1], hacc[t]);
      yacc[t] = MFMA16(axh[c], wsf[c][t][0], yacc[t]);
      yacc[t] = MFMA16(axl[c], wsf[c][t][0], yacc[t]);
      yacc[t] = MFMA16(axh[c], wsf[c][t][1], yacc[t]);
    }

  float* hb = hbuf[wave];
#pragma unroll
  for (int t = 0; t < 2; t++)
#pragma unroll
    for (int r = 0; r < 4; r++)
      hb[(q*4+r)*36 + m + 16*t] = fmaxf(hacc[t][r], 0.f);
  __syncthreads();
  float hv[8];
#pragma unroll
  for (int j = 0; j < 8; j++) hv[j] = hb[m*36 + q*8 + j];
  bf16x8 hh, hl; split8(hv, hh, hl);
#pragma unroll
  for (int t = 0; t < 2; t++) {
    yacc[t] = MFMA16(hh, w1f[t][0], yacc[t]);
    yacc[t] = MFMA16(hl, w1f[t][0], yacc[t]);
    yacc[t] = MFMA16(hh, w1f[t][1], yacc[t]);
  }

#pragma unroll
  for (int t = 0; t < 2; t++)
#pragma unroll
    for (int r = 0; r < 4; r++)
      net[(size_t)(pbase + q*4 + r)*32 + m + 16*t] = yacc[t][r];
}

// final stage + fc_c via MFMA
__global__ __launch_bounds__(256) void k_final_m(
    float* __restrict__ net, const int* __restrict__ gsort,
    const float* __restrict__ pooled,
    const ushort_t* __restrict__ wp, const ushort_t* __restrict__ wpc,
    const float* __restrict__ b0, const float* __restrict__ b1,
    const float* __restrict__ bc)
{
  __shared__ float hbuf[4][16*36];
  __shared__ float ybuf[4][16*36];
  int wave = threadIdx.x >> 6, lane = threadIdx.x & 63;
  int m = lane & 15, q = lane >> 4;
  int pbase = (blockIdx.x*4 + wave)*16;
  int pt = pbase + m;

  bf16x8 w0f[2][2][2], wsf[2][2][2], w1f[2][2], wcf[2][2];
#pragma unroll
  for (int c = 0; c < 2; c++)
#pragma unroll
    for (int t = 0; t < 2; t++)
#pragma unroll
      for (int e = 0; e < 2; e++) {
        w0f[c][t][e] = *(const bf16x8*)(wp + ((size_t)(((c*2+t)*2+e)    )*64 + lane)*8);
        wsf[c][t][e] = *(const bf16x8*)(wp + ((size_t)(((c*2+t)*2+e) + 8)*64 + lane)*8);
      }
#pragma unroll
  for (int t = 0; t < 2; t++)
#pragma unroll
    for (int e = 0; e < 2; e++) {
      w1f[t][e] = *(const bf16x8*)(wp  + ((size_t)(16 + t*2 + e)*64 + lane)*8);
      wcf[t][e] = *(const bf16x8*)(wpc + ((size_t)(     t*2 + e)*64 + lane)*8);
    }

  float xv[2][8];
  {
    const float* a = net + (size_t)pt*32 + q*8;
    *(f32x4*)&xv[0][0] = *(const f32x4*)a;
    *(f32x4*)&xv[0][4] = *(const f32x4*)(a+4);
    int g = gsort[pt];
    const float* b = pooled + (size_t)g*32 + q*8;
    *(f32x4*)&xv[1][0] = *(const f32x4*)b;
    *(f32x4*)&xv[1][4] = *(const f32x4*)(b+4);
  }

  bf16x8 axh[2], axl[2], arh[2], arl[2];
#pragma unroll
  for (int c = 0; c < 2; c++) {
    float r[8];
#pragma unroll
    for (int j = 0; j < 8; j++) r[j] = fmaxf(xv[c][j], 0.f);
    split8(xv[c], axh[c], axl[c]);
    split8(r,     arh[c], arl[c]);
  }

  f32x4 hacc[2], yacc[2];
#pragma unroll
  for (int t = 0; t < 2; t++) {
    float bb0 = b0[m + 16*t], bb1 = b1[m + 16*t];
    hacc[t] = (f32x4){bb0,bb0,bb0,bb0};
    yacc[t] = (f32x4){bb1,bb1,bb1,bb1};
  }

#pragma unroll
  for (int c = 0; c < 2; c++)
#pragma unroll
    for (int t = 0; t < 2; t++) {
      hacc[t] = MFMA16(arh[c], w0f[c][t][0], hacc[t]);
      hacc[t] = MFMA16(arl[c], w0f[c][t][0], hacc[t]);
      hacc[t] = MFMA16(arh[c], w0f[c][t][1], hacc[t]);
      yacc[t] = MFMA16(axh[c], wsf[c][t][0], yacc[t]);
      yacc[t] = MFMA16(axl[c], wsf[c][t][0], yacc[t]);
      yacc[t] = MFMA16(axh[c], wsf[c][t][1], yacc[t]);
    }

  float* hb = hbuf[wave];
#pragma unroll
  for (int t = 0; t < 2; t++)
#pragma unroll
    for (int r = 0; r < 4; r++)
      hb[(q*4+r)*36 + m + 16*t] = fmaxf(hacc[t][r], 0.f);
  __syncthreads();
  float hv[8];
#pragma unroll
  for (int j = 0; j < 8; j++) hv[j] = hb[m*36 + q*8 + j];
  bf16x8 hh, hl; split8(hv, hh, hl);
#pragma unroll
  for (int t = 0; t < 2; t++) {
    yacc[t] = MFMA16(hh, w1f[t][0], yacc[t]);
    yacc[t] = MFMA16(hl, w1f[t][0], yacc[t]);
    yacc[t] = MFMA16(hh, w1f[t][1], yacc[t]);
  }

  // y -> A-layout via LDS for fc_c
  float* yb = ybuf[wave];
#pragma unroll
  for (int t = 0; t < 2; t++)
#pragma unroll
    for (int r = 0; r < 4; r++)
      yb[(q*4+r)*36 + m + 16*t] = yacc[t][r];
  __syncthreads();
  float yv[8];
#pragma unroll
  for (int j = 0; j < 8; j++) yv[j] = yb[m*36 + q*8 + j];
  bf16x8 yh, yl; split8(yv, yh, yl);

  f32x4 cacc[2];
#pragma unroll
  for (int t = 0; t < 2; t++) {
    float bb = bc[m + 16*t];
    cacc[t] = (f32x4){bb,bb,bb,bb};
    cacc[t] = MFMA16(yh, wcf[t][0], cacc[t]);
    cacc[t] = MFMA16(yl, wcf[t][0], cacc[t]);
    cacc[t] = MFMA16(yh, wcf[t][1], cacc[t]);
  }

#pragma unroll
  for (int t = 0; t < 2; t++)
#pragma unroll
    for (int r = 0; r < 4; r++)
      net[(size_t)(pbase + q*4 + r)*32 + m + 16*t] = cacc[t][r];
}

// AoS pool: 8 threads per cell, each float4 of 4 channels
__global__ __launch_bounds__(256) void k_pool(
    const float* __restrict__ net, const int* __restrict__ start,
    float* __restrict__ pooled)
{
  int tid = blockIdx.x*256 + threadIdx.x;   // [0, BG*8)
  int c = tid >> 3, sub = tid & 7;
  int s = start[c], e = start[c+1];
  f32x4 mx = (f32x4){-INFINITY,-INFINITY,-INFINITY,-INFINITY};
  for (int k = s; k < e; k++) {
    f32x4 v = *(const f32x4*)(net + (size_t)k*32 + sub*4);
    mx.x = fmaxf(mx.x, v.x); mx.y = fmaxf(mx.y, v.y);
    mx.z = fmaxf(mx.z, v.z); mx.w = fmaxf(mx.w, v.w);
  }
  *(f32x4*)(pooled + (size_t)c*32 + sub*4) = mx;
}

// AoS mean -> out[b][ch][cell]; empty cells -> 0
__global__ __launch_bounds__(256) void k_mean(
    const float* __restrict__ net, const int* __restrict__ start,
    float* __restrict__ outp)
{
  int tid = blockIdx.x*256 + threadIdx.x;   // [0, BG*8)
  int c = tid >> 3, sub = tid & 7;
  int s = start[c], e = start[c+1];
  f32x4 sum = (f32x4){0.f,0.f,0.f,0.f};
  for (int k = s; k < e; k++) {
    f32x4 v = *(const f32x4*)(net + (size_t)k*32 + sub*4);
    sum.x += v.x; sum.y += v.y; sum.z += v.z; sum.w += v.w;
  }
  float inv = (e > s) ? 1.f/(float)(e - s) : 0.f;
  int b = c >> 15, cell = c & 32767;
  size_t ob = ((size_t)b << 20) + cell;
#pragma unroll
  for (int jj = 0; jj < 4; jj++) {
    int ch = sub*4 + jj;
    float v = ((const float*)&sum)[jj] * inv;
    outp[ob + ((size_t)ch << 15)] = v;
  }
}

extern "C" void kernel_launch(void* const* d_in, const int* in_sizes, int n_in,
                              void* d_out, int out_size, void* d_ws, size_t ws_size,
                              hipStream_t stream)
{
  const float* p   = (const float*)d_in[0];
  const float* Wp  = (const float*)d_in[1];
  const float* bp  = (const float*)d_in[2];
  const float* f0w = (const float*)d_in[3];
  const float* f0b = (const float*)d_in[4];
  const float* f1w = (const float*)d_in[5];
  const float* f1b = (const float*)d_in[6];
  const float* scw = (const float*)d_in[7];
  const float* wc  = (const float*)d_in[8];
  const float* bc  = (const float*)d_in[9];
  float* outp = (float*)d_out;

  char* wsb = (char*)d_ws;
  float*    net      = (float*)wsb;                       // NPTS*32 f32 = 51.2 MB
  float*    pooled   = net + (size_t)NPTS*32;             // BG*32 f32 = 8.4 MB
  int*      gbuf     = (int*)(pooled + (size_t)BG*32);    // NPTS
  int*      gsort    = gbuf + NPTS;                       // NPTS
  int*      hist     = gsort + NPTS;                      // BG
  int*      start    = hist + BG;                         // BG+1
  int*      cursor   = start + BG + 1;                    // BG
  ushort_t* wpack    = (ushort_t*)(cursor + BG);          // 104*512 ushort
  float*    p_sorted = (float*)(wpack + (size_t)104*512); // NPTS*3

  dim3 blk(256);
  dim3 gpts((NPTS + 255)/256);
  dim3 gmfma(NPTS/64);          // 6250 blocks, 4 waves x 16 pts
  dim3 gcell((BG*8)/256);       // 2048 blocks

  hipMemsetAsync(hist, 0, (size_t)BG*4, stream);
  hipLaunchKernelGGL(k_hist, gpts, blk, 0, stream, p, gbuf, hist);
  hipLaunchKernelGGL(k_scan, dim3(1), dim3(1024), 0, stream, hist, start, cursor);
  hipLaunchKernelGGL(k_scatter, gpts, blk, 0, stream, p, gbuf, cursor, p_sorted, gsort);
  hipLaunchKernelGGL(k_pack, dim3(104), dim3(64), 0, stream, f0w, scw, f1w, wc, wpack);
  hipLaunchKernelGGL(k_fused0, gmfma, blk, 0, stream,
                     p_sorted, Wp, bp, wpack + (size_t)0*20*512,
                     f0b + 0*32, f1b + 0*32, net);
  hipLaunchKernelGGL(k_pool, gcell, blk, 0, stream, net, start, pooled);
  hipLaunchKernelGGL(k_stage_m, gmfma, blk, 0, stream, net, gsort, pooled,
                     wpack + (size_t)1*20*512, f0b + 1*32, f1b + 1*32);
  hipLaunchKernelGGL(k_pool, gcell, blk, 0, stream, net, start, pooled);
  hipLaunchKernelGGL(k_stage_m, gmfma, blk, 0, stream, net, gsort, pooled,
                     wpack + (size_t)2*20*512, f0b + 2*32, f1b + 2*32);
  hipLaunchKernelGGL(k_pool, gcell, blk, 0, stream, net, start, pooled);
  hipLaunchKernelGGL(k_stage_m, gmfma, blk, 0, stream, net, gsort, pooled,
                     wpack + (size_t)3*20*512, f0b + 3*32, f1b + 3*32);
  hipLaunchKernelGGL(k_pool, gcell, blk, 0, stream, net, start, pooled);
  hipLaunchKernelGGL(k_final_m, gmfma, blk, 0, stream, net, gsort, pooled,
                     wpack + (size_t)4*20*512, wpack + (size_t)100*512,
                     f0b + 4*32, f1b + 4*32, bc);
  hipLaunchKernelGGL(k_mean, gcell, blk, 0, stream, net, start, outp);
}

// Round 10
// 392.327 us; speedup vs baseline: 2.0117x; 1.0913x over previous
//
#include <hip/hip_runtime.h>
#include <math.h>

#define TPTS 200000
#define BB 2
#define NPTS (BB*TPTS)
#define GRID3 32768
#define BG 65536   // BB * GRID3

typedef __attribute__((ext_vector_type(8))) __bf16 bf16x8;
typedef __attribute__((ext_vector_type(4))) float f32x4;
typedef unsigned short ushort_t;

#define MFMA16(a,b,c) __builtin_amdgcn_mfma_f32_16x16x32_bf16(a,b,c,0,0,0)

__device__ __forceinline__ void split8(const float* v, bf16x8& hi, bf16x8& lo)
{
#pragma unroll
  for (int j = 0; j < 8; j++) {
    float f = v[j];
    __bf16 h = (__bf16)f;
    hi[j] = h;
    lo[j] = (__bf16)(f - (float)h);   // exact residual, rounded to bf16
  }
}

// cell id: must match reference fp32 arithmetic exactly
__device__ __forceinline__ int cellof(float p0, float p1, float p2, int t)
{
  const float DEN = (float)(1.0 + 0.1 + 1e-3);
  const float HI  = (float)(1.0 - 1e-3);
  float n0 = fminf(fmaxf(p0/DEN + 0.5f, 0.f), HI);
  float n1 = fminf(fmaxf(p1/DEN + 0.5f, 0.f), HI);
  float n2 = fminf(fmaxf(p2/DEN + 0.5f, 0.f), HI);
  int c0 = (int)floorf(n0*32.f), c1 = (int)floorf(n1*32.f), c2 = (int)floorf(n2*32.f);
  return c0 + 32*(c1 + 32*c2) + (t >= TPTS ? GRID3 : 0);
}

__global__ __launch_bounds__(256) void k_hist(
    const float* __restrict__ p, int* __restrict__ gbuf, int* __restrict__ hist)
{
  int t = blockIdx.x*256 + threadIdx.x;
  if (t >= NPTS) return;
  int g = cellof(p[3*t], p[3*t+1], p[3*t+2], t);
  gbuf[t] = g;
  atomicAdd(hist + g, 1);
}

__global__ __launch_bounds__(1024) void k_scan(
    const int* __restrict__ hist, int* __restrict__ start, int* __restrict__ cursor)
{
  __shared__ int sums[1024];
  const int tid = threadIdx.x;
  const int base = tid * (BG/1024);
  int acc = 0;
#pragma unroll 4
  for (int k = 0; k < BG/1024; k++) acc += hist[base+k];
  sums[tid] = acc;
  __syncthreads();
  for (int off = 1; off < 1024; off <<= 1) {
    int v = sums[tid];
    int u = (tid >= off) ? sums[tid-off] : 0;
    __syncthreads();
    sums[tid] = v + u;
    __syncthreads();
  }
  int run = (tid > 0) ? sums[tid-1] : 0;
#pragma unroll 4
  for (int k = 0; k < BG/1024; k++) {
    start[base+k] = run; cursor[base+k] = run;
    run += hist[base+k];
  }
  if (tid == 1023) start[BG] = sums[1023];
}

__global__ __launch_bounds__(256) void k_scatter(
    const float* __restrict__ p, const int* __restrict__ gbuf,
    int* __restrict__ cursor, float* __restrict__ p_sorted, int* __restrict__ gsort)
{
  int t = blockIdx.x*256 + threadIdx.x;
  if (t >= NPTS) return;
  int g = gbuf[t];
  int slot = atomicAdd(cursor + g, 1);
  gsort[slot] = g;
  p_sorted[3*slot]   = p[3*t];
  p_sorted[3*slot+1] = p[3*t+1];
  p_sorted[3*slot+2] = p[3*t+2];
}

// pack weights into MFMA B-fragment order (bf16 hi/lo), once.
// frags 0..99: resblock stages; 100..103: wc; 104..119: Wp (60x64, zero-padded K)
__global__ void k_pack(
    const float* __restrict__ f0w, const float* __restrict__ scw,
    const float* __restrict__ f1w, const float* __restrict__ wc,
    const float* __restrict__ Wp,
    ushort_t* __restrict__ wpack)
{
  int f = blockIdx.x, l = threadIdx.x;
  if (f >= 104) {
    // Wp fragments: idx = c*8 + t*2 + e ; k = c*32 + (l>>4)*8 + j ; n = t*16 + (l&15)
    int idx = f - 104;
    int c = idx >> 3, t = (idx >> 1) & 3, e = idx & 1;
#pragma unroll
    for (int j = 0; j < 8; j++) {
      int k = c*32 + (l>>4)*8 + j, n = t*16 + (l&15);
      float v = (k < 60) ? Wp[k*64 + n] : 0.f;
      __bf16 h = (__bf16)v;
      __bf16 out = (e == 0) ? h : (__bf16)(v - (float)h);
      union { __bf16 b; ushort_t u; } cv; cv.b = out;
      wpack[((size_t)f*64 + l)*8 + j] = cv.u;
    }
    return;
  }
  const float* W; int c, t, e;
  if (f < 100) {
    int s = f / 20, r = f % 20;
    if (r < 8)       { W = f0w + s*2048; c = r>>2;        t = (r>>1)&1; e = r&1; }
    else if (r < 16) { int q = r-8;  W = scw + s*2048; c = q>>2; t = (q>>1)&1; e = q&1; }
    else             { int q = r-16; W = f1w + s*1024; c = 0;    t = q>>1;     e = q&1; }
  } else { int q = f-100; W = wc; c = 0; t = q>>1; e = q&1; }
#pragma unroll
  for (int j = 0; j < 8; j++) {
    int k = c*32 + (l>>4)*8 + j, n = t*16 + (l&15);
    float v = W[k*32 + n];
    __bf16 h = (__bf16)v;
    __bf16 out = (e == 0) ? h : (__bf16)(v - (float)h);
    union { __bf16 b; ushort_t u; } cv; cv.b = out;
    wpack[((size_t)f*64 + l)*8 + j] = cv.u;
  }
}

// FUSED: per-lane PE entries (A-frag layout) -> MFMA fc_pos -> LDS transpose
// -> MFMA resblock0 -> net AoS [pt][32]. No xbuf, no 960-FMA posenc.
__global__ __launch_bounds__(256) void k_fused0(
    const float* __restrict__ ps,
    const ushort_t* __restrict__ wpPE, const float* __restrict__ bp,
    const ushort_t* __restrict__ wp,
    const float* __restrict__ b0, const float* __restrict__ b1,
    float* __restrict__ net)
{
  __shared__ float xlds[4][16*68];
  __shared__ float hbuf[4][16*36];
  int wave = threadIdx.x >> 6, lane = threadIdx.x & 63;
  int m = lane & 15, q = lane >> 4;
  int pbase = (blockIdx.x*4 + wave)*16;
  int pt = pbase + m;

  // ---- phase 1: positional encoding entries for this lane's A-fragment ----
  float p0 = ps[3*pt], p1 = ps[3*pt+1], p2 = ps[3*pt+2];
  float u0 = 2.f*p0 - 1.f, u1 = 2.f*p1 - 1.f, u2 = 2.f*p2 - 1.f;
  const float PIF = 3.14159265358979323846f;

  float pe[2][8];
#pragma unroll
  for (int c2 = 0; c2 < 2; c2++) {
#pragma unroll
    for (int jj = 0; jj < 8; jj++) {
      int e = c2*32 + q*8 + jj;          // PE row index (runtime via q)
      int l = (e * 43691) >> 18;         // e / 6 (valid e < 2^17)
      int r = e - l*6;
      bool issin = (r < 3);
      int d = issin ? r : (r - 3);
      float ud = (d == 0) ? u0 : ((d == 1) ? u1 : u2);
      float xval = ldexpf(ud, l);                    // exact *2^l
      float red = xval - 2.f*rintf(0.5f*xval);       // exact mod-2
      float s, cc;
      __sincosf(PIF*red, &s, &cc);
      float v = issin ? s : cc;
      pe[c2][jj] = (e < 60) ? v : 0.f;               // zero-pad K 60->64
    }
  }
  bf16x8 peh[2], pel[2];
  split8(pe[0], peh[0], pel[0]);
  split8(pe[1], peh[1], pel[1]);

  // x = PE @ Wp + bp  (4 N-tiles)
  f32x4 xacc[4];
#pragma unroll
  for (int t = 0; t < 4; t++) {
    float bb = bp[t*16 + m];
    xacc[t] = (f32x4){bb,bb,bb,bb};
  }
#pragma unroll
  for (int c2 = 0; c2 < 2; c2++)
#pragma unroll
    for (int t = 0; t < 4; t++) {
      bf16x8 bh = *(const bf16x8*)(wpPE + ((size_t)((c2*4+t)*2    )*64 + lane)*8);
      bf16x8 bl = *(const bf16x8*)(wpPE + ((size_t)((c2*4+t)*2 + 1)*64 + lane)*8);
      xacc[t] = MFMA16(peh[c2], bh, xacc[t]);
      xacc[t] = MFMA16(pel[c2], bh, xacc[t]);
      xacc[t] = MFMA16(peh[c2], bl, xacc[t]);
    }

  // D-layout -> A-layout via LDS (stride 68: 2-way max, free)
  float* xl = xlds[wave];
#pragma unroll
  for (int t = 0; t < 4; t++)
#pragma unroll
    for (int r = 0; r < 4; r++)
      xl[(q*4+r)*68 + t*16 + m] = xacc[t][r];
  __syncthreads();

  float xv[2][8];
#pragma unroll
  for (int c2 = 0; c2 < 2; c2++)
#pragma unroll
    for (int jj = 0; jj < 8; jj++)
      xv[c2][jj] = xl[m*68 + c2*32 + q*8 + jj];

  // ---- phase 2: resblock0 via MFMA ----
  bf16x8 w0f[2][2][2], wsf[2][2][2], w1f[2][2];
#pragma unroll
  for (int c = 0; c < 2; c++)
#pragma unroll
    for (int t = 0; t < 2; t++)
#pragma unroll
      for (int e = 0; e < 2; e++) {
        w0f[c][t][e] = *(const bf16x8*)(wp + ((size_t)(((c*2+t)*2+e)    )*64 + lane)*8);
        wsf[c][t][e] = *(const bf16x8*)(wp + ((size_t)(((c*2+t)*2+e) + 8)*64 + lane)*8);
      }
#pragma unroll
  for (int t = 0; t < 2; t++)
#pragma unroll
    for (int e = 0; e < 2; e++)
      w1f[t][e] = *(const bf16x8*)(wp + ((size_t)(16 + t*2 + e)*64 + lane)*8);

  bf16x8 axh[2], axl[2], arh[2], arl[2];
#pragma unroll
  for (int c = 0; c < 2; c++) {
    float r[8];
#pragma unroll
    for (int j = 0; j < 8; j++) r[j] = fmaxf(xv[c][j], 0.f);
    split8(xv[c], axh[c], axl[c]);
    split8(r,     arh[c], arl[c]);
  }

  f32x4 hacc[2], yacc[2];
#pragma unroll
  for (int t = 0; t < 2; t++) {
    float bb0 = b0[m + 16*t], bb1 = b1[m + 16*t];
    hacc[t] = (f32x4){bb0,bb0,bb0,bb0};
    yacc[t] = (f32x4){bb1,bb1,bb1,bb1};
  }

#pragma unroll
  for (int c = 0; c < 2; c++)
#pragma unroll
    for (int t = 0; t < 2; t++) {
      hacc[t] = MFMA16(arh[c], w0f[c][t][0], hacc[t]);
      hacc[t] = MFMA16(arl[c], w0f[c][t][0], hacc[t]);
      hacc[t] = MFMA16(arh[c], w0f[c][t][1], hacc[t]);
      yacc[t] = MFMA16(axh[c], wsf[c][t][0], yacc[t]);
      yacc[t] = MFMA16(axl[c], wsf[c][t][0], yacc[t]);
      yacc[t] = MFMA16(axh[c], wsf[c][t][1], yacc[t]);
    }

  float* hb = hbuf[wave];
#pragma unroll
  for (int t = 0; t < 2; t++)
#pragma unroll
    for (int r = 0; r < 4; r++)
      hb[(q*4+r)*36 + m + 16*t] = fmaxf(hacc[t][r], 0.f);
  __syncthreads();
  float hv[8];
#pragma unroll
  for (int j = 0; j < 8; j++) hv[j] = hb[m*36 + q*8 + j];
  bf16x8 hh, hl; split8(hv, hh, hl);
#pragma unroll
  for (int t = 0; t < 2; t++) {
    yacc[t] = MFMA16(hh, w1f[t][0], yacc[t]);
    yacc[t] = MFMA16(hl, w1f[t][0], yacc[t]);
    yacc[t] = MFMA16(hh, w1f[t][1], yacc[t]);
  }

#pragma unroll
  for (int t = 0; t < 2; t++)
#pragma unroll
    for (int r = 0; r < 4; r++)
      net[(size_t)(pbase + q*4 + r)*32 + m + 16*t] = yacc[t][r];
}

// middle stages via MFMA: x = [net[pt], pooled[g]] -> net
__global__ __launch_bounds__(256) void k_stage_m(
    float* __restrict__ net, const int* __restrict__ gsort,
    const float* __restrict__ pooled,
    const ushort_t* __restrict__ wp,
    const float* __restrict__ b0, const float* __restrict__ b1)
{
  __shared__ float hbuf[4][16*36];
  int wave = threadIdx.x >> 6, lane = threadIdx.x & 63;
  int m = lane & 15, q = lane >> 4;
  int pbase = (blockIdx.x*4 + wave)*16;
  int pt = pbase + m;

  bf16x8 w0f[2][2][2], wsf[2][2][2], w1f[2][2];
#pragma unroll
  for (int c = 0; c < 2; c++)
#pragma unroll
    for (int t = 0; t < 2; t++)
#pragma unroll
      for (int e = 0; e < 2; e++) {
        w0f[c][t][e] = *(const bf16x8*)(wp + ((size_t)(((c*2+t)*2+e)    )*64 + lane)*8);
        wsf[c][t][e] = *(const bf16x8*)(wp + ((size_t)(((c*2+t)*2+e) + 8)*64 + lane)*8);
      }
#pragma unroll
  for (int t = 0; t < 2; t++)
#pragma unroll
    for (int e = 0; e < 2; e++)
      w1f[t][e] = *(const bf16x8*)(wp + ((size_t)(16 + t*2 + e)*64 + lane)*8);

  float xv[2][8];
  {
    const float* a = net + (size_t)pt*32 + q*8;
    *(f32x4*)&xv[0][0] = *(const f32x4*)a;
    *(f32x4*)&xv[0][4] = *(const f32x4*)(a+4);
    int g = gsort[pt];
    const float* b = pooled + (size_t)g*32 + q*8;
    *(f32x4*)&xv[1][0] = *(const f32x4*)b;
    *(f32x4*)&xv[1][4] = *(const f32x4*)(b+4);
  }

  bf16x8 axh[2], axl[2], arh[2], arl[2];
#pragma unroll
  for (int c = 0; c < 2; c++) {
    float r[8];
#pragma unroll
    for (int j = 0; j < 8; j++) r[j] = fmaxf(xv[c][j], 0.f);
    split8(xv[c], axh[c], axl[c]);
    split8(r,     arh[c], arl[c]);
  }

  f32x4 hacc[2], yacc[2];
#pragma unroll
  for (int t = 0; t < 2; t++) {
    float bb0 = b0[m + 16*t], bb1 = b1[m + 16*t];
    hacc[t] = (f32x4){bb0,bb0,bb0,bb0};
    yacc[t] = (f32x4){bb1,bb1,bb1,bb1};
  }

#pragma unroll
  for (int c = 0; c < 2; c++)
#pragma unroll
    for (int t = 0; t < 2; t++) {
      hacc[t] = MFMA16(arh[c], w0f[c][t][0], hacc[t]);
      hacc[t] = MFMA16(arl[c], w0f[c][t][0], hacc[t]);
      hacc[t] = MFMA16(arh[c], w0f[c][t][1], hacc[t]);
      yacc[t] = MFMA16(axh[c], wsf[c][t][0], yacc[t]);
      yacc[t] = MFMA16(axl[c], wsf[c][t][0], yacc[t]);
      yacc[t] = MFMA16(axh[c], wsf[c][t][1], yacc[t]);
    }

  float* hb = hbuf[wave];
#pragma unroll
  for (int t = 0; t < 2; t++)
#pragma unroll
    for (int r = 0; r < 4; r++)
      hb[(q*4+r)*36 + m + 16*t] = fmaxf(hacc[t][r], 0.f);
  __syncthreads();
  float hv[8];
#pragma unroll
  for (int j = 0; j < 8; j++) hv[j] = hb[m*36 + q*8 + j];
  bf16x8 hh, hl; split8(hv, hh, hl);
#pragma unroll
  for (int t = 0; t < 2; t++) {
    yacc[t] = MFMA16(hh, w1f[t][0], yacc[t]);
    yacc[t] = MFMA16(hl, w1f[t][0], yacc[t]);
    yacc[t] = MFMA16(hh, w1f[t][1], yacc[t]);
  }

#pragma unroll
  for (int t = 0; t < 2; t++)
#pragma unroll
    for (int r = 0; r < 4; r++)
      net[(size_t)(pbase + q*4 + r)*32 + m + 16*t] = yacc[t][r];
}

// final stage + fc_c via MFMA
__global__ __launch_bounds__(256) void k_final_m(
    float* __restrict__ net, const int* __restrict__ gsort,
    const float* __restrict__ pooled,
    const ushort_t* __restrict__ wp, const ushort_t* __restrict__ wpc,
    const float* __restrict__ b0, const float* __restrict__ b1,
    const float* __restrict__ bc)
{
  __shared__ float hbuf[4][16*36];
  __shared__ float ybuf[4][16*36];
  int wave = threadIdx.x >> 6, lane = threadIdx.x & 63;
  int m = lane & 15, q = lane >> 4;
  int pbase = (blockIdx.x*4 + wave)*16;
  int pt = pbase + m;

  bf16x8 w0f[2][2][2], wsf[2][2][2], w1f[2][2], wcf[2][2];
#pragma unroll
  for (int c = 0; c < 2; c++)
#pragma unroll
    for (int t = 0; t < 2; t++)
#pragma unroll
      for (int e = 0; e < 2; e++) {
        w0f[c][t][e] = *(const bf16x8*)(wp + ((size_t)(((c*2+t)*2+e)    )*64 + lane)*8);
        wsf[c][t][e] = *(const bf16x8*)(wp + ((size_t)(((c*2+t)*2+e) + 8)*64 + lane)*8);
      }
#pragma unroll
  for (int t = 0; t < 2; t++)
#pragma unroll
    for (int e = 0; e < 2; e++) {
      w1f[t][e] = *(const bf16x8*)(wp  + ((size_t)(16 + t*2 + e)*64 + lane)*8);
      wcf[t][e] = *(const bf16x8*)(wpc + ((size_t)(     t*2 + e)*64 + lane)*8);
    }

  float xv[2][8];
  {
    const float* a = net + (size_t)pt*32 + q*8;
    *(f32x4*)&xv[0][0] = *(const f32x4*)a;
    *(f32x4*)&xv[0][4] = *(const f32x4*)(a+4);
    int g = gsort[pt];
    const float* b = pooled + (size_t)g*32 + q*8;
    *(f32x4*)&xv[1][0] = *(const f32x4*)b;
    *(f32x4*)&xv[1][4] = *(const f32x4*)(b+4);
  }

  bf16x8 axh[2], axl[2], arh[2], arl[2];
#pragma unroll
  for (int c = 0; c < 2; c++) {
    float r[8];
#pragma unroll
    for (int j = 0; j < 8; j++) r[j] = fmaxf(xv[c][j], 0.f);
    split8(xv[c], axh[c], axl[c]);
    split8(r,     arh[c], arl[c]);
  }

  f32x4 hacc[2], yacc[2];
#pragma unroll
  for (int t = 0; t < 2; t++) {
    float bb0 = b0[m + 16*t], bb1 = b1[m + 16*t];
    hacc[t] = (f32x4){bb0,bb0,bb0,bb0};
    yacc[t] = (f32x4){bb1,bb1,bb1,bb1};
  }

#pragma unroll
  for (int c = 0; c < 2; c++)
#pragma unroll
    for (int t = 0; t < 2; t++) {
      hacc[t] = MFMA16(arh[c], w0f[c][t][0], hacc[t]);
      hacc[t] = MFMA16(arl[c], w0f[c][t][0], hacc[t]);
      hacc[t] = MFMA16(arh[c], w0f[c][t][1], hacc[t]);
      yacc[t] = MFMA16(axh[c], wsf[c][t][0], yacc[t]);
      yacc[t] = MFMA16(axl[c], wsf[c][t][0], yacc[t]);
      yacc[t] = MFMA16(axh[c], wsf[c][t][1], yacc[t]);
    }

  float* hb = hbuf[wave];
#pragma unroll
  for (int t = 0; t < 2; t++)
#pragma unroll
    for (int r = 0; r < 4; r++)
      hb[(q*4+r)*36 + m + 16*t] = fmaxf(hacc[t][r], 0.f);
  __syncthreads();
  float hv[8];
#pragma unroll
  for (int j = 0; j < 8; j++) hv[j] = hb[m*36 + q*8 + j];
  bf16x8 hh, hl; split8(hv, hh, hl);
#pragma unroll
  for (int t = 0; t < 2; t++) {
    yacc[t] = MFMA16(hh, w1f[t][0], yacc[t]);
    yacc[t] = MFMA16(hl, w1f[t][0], yacc[t]);
    yacc[t] = MFMA16(hh, w1f[t][1], yacc[t]);
  }

  // y -> A-layout via LDS for fc_c
  float* yb = ybuf[wave];
#pragma unroll
  for (int t = 0; t < 2; t++)
#pragma unroll
    for (int r = 0; r < 4; r++)
      yb[(q*4+r)*36 + m + 16*t] = yacc[t][r];
  __syncthreads();
  float yv[8];
#pragma unroll
  for (int j = 0; j < 8; j++) yv[j] = yb[m*36 + q*8 + j];
  bf16x8 yh, yl; split8(yv, yh, yl);

  f32x4 cacc[2];
#pragma unroll
  for (int t = 0; t < 2; t++) {
    float bb = bc[m + 16*t];
    cacc[t] = (f32x4){bb,bb,bb,bb};
    cacc[t] = MFMA16(yh, wcf[t][0], cacc[t]);
    cacc[t] = MFMA16(yl, wcf[t][0], cacc[t]);
    cacc[t] = MFMA16(yh, wcf[t][1], cacc[t]);
  }

#pragma unroll
  for (int t = 0; t < 2; t++)
#pragma unroll
    for (int r = 0; r < 4; r++)
      net[(size_t)(pbase + q*4 + r)*32 + m + 16*t] = cacc[t][r];
}

// AoS pool: 8 threads per cell, each float4 of 4 channels
__global__ __launch_bounds__(256) void k_pool(
    const float* __restrict__ net, const int* __restrict__ start,
    float* __restrict__ pooled)
{
  int tid = blockIdx.x*256 + threadIdx.x;   // [0, BG*8)
  int c = tid >> 3, sub = tid & 7;
  int s = start[c], e = start[c+1];
  f32x4 mx = (f32x4){-INFINITY,-INFINITY,-INFINITY,-INFINITY};
  for (int k = s; k < e; k++) {
    f32x4 v = *(const f32x4*)(net + (size_t)k*32 + sub*4);
    mx.x = fmaxf(mx.x, v.x); mx.y = fmaxf(mx.y, v.y);
    mx.z = fmaxf(mx.z, v.z); mx.w = fmaxf(mx.w, v.w);
  }
  *(f32x4*)(pooled + (size_t)c*32 + sub*4) = mx;
}

// AoS mean -> out[b][ch][cell]; empty cells -> 0
__global__ __launch_bounds__(256) void k_mean(
    const float* __restrict__ net, const int* __restrict__ start,
    float* __restrict__ outp)
{
  int tid = blockIdx.x*256 + threadIdx.x;   // [0, BG*8)
  int c = tid >> 3, sub = tid & 7;
  int s = start[c], e = start[c+1];
  f32x4 sum = (f32x4){0.f,0.f,0.f,0.f};
  for (int k = s; k < e; k++) {
    f32x4 v = *(const f32x4*)(net + (size_t)k*32 + sub*4);
    sum.x += v.x; sum.y += v.y; sum.z += v.z; sum.w += v.w;
  }
  float inv = (e > s) ? 1.f/(float)(e - s) : 0.f;
  int b = c >> 15, cell = c & 32767;
  size_t ob = ((size_t)b << 20) + cell;
#pragma unroll
  for (int jj = 0; jj < 4; jj++) {
    int ch = sub*4 + jj;
    float v = ((const float*)&sum)[jj] * inv;
    outp[ob + ((size_t)ch << 15)] = v;
  }
}

extern "C" void kernel_launch(void* const* d_in, const int* in_sizes, int n_in,
                              void* d_out, int out_size, void* d_ws, size_t ws_size,
                              hipStream_t stream)
{
  const float* p   = (const float*)d_in[0];
  const float* Wp  = (const float*)d_in[1];
  const float* bp  = (const float*)d_in[2];
  const float* f0w = (const float*)d_in[3];
  const float* f0b = (const float*)d_in[4];
  const float* f1w = (const float*)d_in[5];
  const float* f1b = (const float*)d_in[6];
  const float* scw = (const float*)d_in[7];
  const float* wc  = (const float*)d_in[8];
  const float* bc  = (const float*)d_in[9];
  float* outp = (float*)d_out;

  char* wsb = (char*)d_ws;
  float*    net      = (float*)wsb;                       // NPTS*32 f32 = 51.2 MB
  float*    pooled   = net + (size_t)NPTS*32;             // BG*32 f32 = 8.4 MB
  int*      gbuf     = (int*)(pooled + (size_t)BG*32);    // NPTS
  int*      gsort    = gbuf + NPTS;                       // NPTS
  int*      hist     = gsort + NPTS;                      // BG
  int*      start    = hist + BG;                         // BG+1
  int*      cursor   = start + BG + 1;                    // BG
  ushort_t* wpack    = (ushort_t*)(cursor + BG);          // 120*512 ushort
  float*    p_sorted = (float*)(wpack + (size_t)120*512); // NPTS*3

  dim3 blk(256);
  dim3 gpts((NPTS + 255)/256);
  dim3 gmfma(NPTS/64);          // 6250 blocks, 4 waves x 16 pts
  dim3 gcell((BG*8)/256);       // 2048 blocks

  hipMemsetAsync(hist, 0, (size_t)BG*4, stream);
  hipLaunchKernelGGL(k_hist, gpts, blk, 0, stream, p, gbuf, hist);
  hipLaunchKernelGGL(k_scan, dim3(1), dim3(1024), 0, stream, hist, start, cursor);
  hipLaunchKernelGGL(k_scatter, gpts, blk, 0, stream, p, gbuf, cursor, p_sorted, gsort);
  hipLaunchKernelGGL(k_pack, dim3(120), dim3(64), 0, stream, f0w, scw, f1w, wc, Wp, wpack);
  hipLaunchKernelGGL(k_fused0, gmfma, blk, 0, stream,
                     p_sorted, wpack + (size_t)104*512, bp,
                     wpack + (size_t)0*20*512, f0b + 0*32, f1b + 0*32, net);
  hipLaunchKernelGGL(k_pool, gcell, blk, 0, stream, net, start, pooled);
  hipLaunchKernelGGL(k_stage_m, gmfma, blk, 0, stream, net, gsort, pooled,
                     wpack + (size_t)1*20*512, f0b + 1*32, f1b + 1*32);
  hipLaunchKernelGGL(k_pool, gcell, blk, 0, stream, net, start, pooled);
  hipLaunchKernelGGL(k_stage_m, gmfma, blk, 0, stream, net, gsort, pooled,
                     wpack + (size_t)2*20*512, f0b + 2*32, f1b + 2*32);
  hipLaunchKernelGGL(k_pool, gcell, blk, 0, stream, net, start, pooled);
  hipLaunchKernelGGL(k_stage_m, gmfma, blk, 0, stream, net, gsort, pooled,
                     wpack + (size_t)3*20*512, f0b + 3*32, f1b + 3*32);
  hipLaunchKernelGGL(k_pool, gcell, blk, 0, stream, net, start, pooled);
  hipLaunchKernelGGL(k_final_m, gmfma, blk, 0, stream, net, gsort, pooled,
                     wpack + (size_t)4*20*512, wpack + (size_t)100*512,
                     f0b + 4*32, f1b + 4*32, bc);
  hipLaunchKernelGGL(k_mean, gcell, blk, 0, stream, net, start, outp);
}

// Round 11
// 327.966 us; speedup vs baseline: 2.4064x; 1.1962x over previous
//
#include <hip/hip_runtime.h>
#include <math.h>

#define TPTS 200000
#define BB 2
#define NPTS (BB*TPTS)
#define GRID3 32768
#define BG 65536   // BB * GRID3
#define SROWS 176  // LDS staging rows per stage block (64 pts + cell overhang; max cell ~30)

typedef __attribute__((ext_vector_type(8))) __bf16 bf16x8;
typedef __attribute__((ext_vector_type(4))) float f32x4;
typedef unsigned short ushort_t;

#define MFMA16(a,b,c) __builtin_amdgcn_mfma_f32_16x16x32_bf16(a,b,c,0,0,0)

__device__ __forceinline__ void split8(const float* v, bf16x8& hi, bf16x8& lo)
{
#pragma unroll
  for (int j = 0; j < 8; j++) {
    float f = v[j];
    __bf16 h = (__bf16)f;
    hi[j] = h;
    lo[j] = (__bf16)(f - (float)h);   // exact residual, rounded to bf16
  }
}

// cell id: must match reference fp32 arithmetic exactly
__device__ __forceinline__ int cellof(float p0, float p1, float p2, int t)
{
  const float DEN = (float)(1.0 + 0.1 + 1e-3);
  const float HI  = (float)(1.0 - 1e-3);
  float n0 = fminf(fmaxf(p0/DEN + 0.5f, 0.f), HI);
  float n1 = fminf(fmaxf(p1/DEN + 0.5f, 0.f), HI);
  float n2 = fminf(fmaxf(p2/DEN + 0.5f, 0.f), HI);
  int c0 = (int)floorf(n0*32.f), c1 = (int)floorf(n1*32.f), c2 = (int)floorf(n2*32.f);
  return c0 + 32*(c1 + 32*c2) + (t >= TPTS ? GRID3 : 0);
}

__global__ __launch_bounds__(256) void k_hist(
    const float* __restrict__ p, int* __restrict__ gbuf, int* __restrict__ hist)
{
  int t = blockIdx.x*256 + threadIdx.x;
  if (t >= NPTS) return;
  int g = cellof(p[3*t], p[3*t+1], p[3*t+2], t);
  gbuf[t] = g;
  atomicAdd(hist + g, 1);
}

// 3-kernel parallel exclusive scan of hist[BG]
__global__ __launch_bounds__(256) void k_scanA(
    const int* __restrict__ hist, int* __restrict__ texcl, int* __restrict__ bsum)
{
  __shared__ int sm[256];
  int tid = threadIdx.x;
  int t = blockIdx.x*256 + tid;
  int v = hist[t];
  sm[tid] = v; __syncthreads();
  for (int off = 1; off < 256; off <<= 1) {
    int x = sm[tid];
    int u = (tid >= off) ? sm[tid-off] : 0;
    __syncthreads();
    sm[tid] = x + u;
    __syncthreads();
  }
  texcl[t] = sm[tid] - v;
  if (tid == 255) bsum[blockIdx.x] = sm[255];
}

__global__ __launch_bounds__(256) void k_scanB(
    const int* __restrict__ bsum, int* __restrict__ boff)
{
  __shared__ int sm[256];
  int tid = threadIdx.x;
  int v = bsum[tid];
  sm[tid] = v; __syncthreads();
  for (int off = 1; off < 256; off <<= 1) {
    int x = sm[tid];
    int u = (tid >= off) ? sm[tid-off] : 0;
    __syncthreads();
    sm[tid] = x + u;
    __syncthreads();
  }
  boff[tid] = sm[tid] - v;   // exclusive block offsets
}

__global__ __launch_bounds__(256) void k_scanC(
    const int* __restrict__ texcl, const int* __restrict__ boff,
    int* __restrict__ start, int* __restrict__ cursor)
{
  int t = blockIdx.x*256 + threadIdx.x;
  int v = boff[blockIdx.x] + texcl[t];
  start[t] = v; cursor[t] = v;
  if (t == 0) start[BG] = NPTS;
}

__global__ __launch_bounds__(256) void k_scatter(
    const float* __restrict__ p, const int* __restrict__ gbuf,
    int* __restrict__ cursor, float* __restrict__ p_sorted, int* __restrict__ gsort)
{
  int t = blockIdx.x*256 + threadIdx.x;
  if (t >= NPTS) return;
  int g = gbuf[t];
  int slot = atomicAdd(cursor + g, 1);
  gsort[slot] = g;
  p_sorted[3*slot]   = p[3*t];
  p_sorted[3*slot+1] = p[3*t+1];
  p_sorted[3*slot+2] = p[3*t+2];
}

// pack weights into MFMA B-fragment order (bf16 hi/lo), once.
// frags 0..99: resblock stages; 100..103: wc; 104..119: Wp (60x64, zero-padded K)
__global__ void k_pack(
    const float* __restrict__ f0w, const float* __restrict__ scw,
    const float* __restrict__ f1w, const float* __restrict__ wc,
    const float* __restrict__ Wp,
    ushort_t* __restrict__ wpack)
{
  int f = blockIdx.x, l = threadIdx.x;
  if (f >= 104) {
    int idx = f - 104;
    int c = idx >> 3, t = (idx >> 1) & 3, e = idx & 1;
#pragma unroll
    for (int j = 0; j < 8; j++) {
      int k = c*32 + (l>>4)*8 + j, n = t*16 + (l&15);
      float v = (k < 60) ? Wp[k*64 + n] : 0.f;
      __bf16 h = (__bf16)v;
      __bf16 out = (e == 0) ? h : (__bf16)(v - (float)h);
      union { __bf16 b; ushort_t u; } cv; cv.b = out;
      wpack[((size_t)f*64 + l)*8 + j] = cv.u;
    }
    return;
  }
  const float* W; int c, t, e;
  if (f < 100) {
    int s = f / 20, r = f % 20;
    if (r < 8)       { W = f0w + s*2048; c = r>>2;        t = (r>>1)&1; e = r&1; }
    else if (r < 16) { int q = r-8;  W = scw + s*2048; c = q>>2; t = (q>>1)&1; e = q&1; }
    else             { int q = r-16; W = f1w + s*1024; c = 0;    t = q>>1;     e = q&1; }
  } else { int q = f-100; W = wc; c = 0; t = q>>1; e = q&1; }
#pragma unroll
  for (int j = 0; j < 8; j++) {
    int k = c*32 + (l>>4)*8 + j, n = t*16 + (l&15);
    float v = W[k*32 + n];
    __bf16 h = (__bf16)v;
    __bf16 out = (e == 0) ? h : (__bf16)(v - (float)h);
    union { __bf16 b; ushort_t u; } cv; cv.b = out;
    wpack[((size_t)f*64 + l)*8 + j] = cv.u;
  }
}

// FUSED: per-lane PE entries (A-frag layout) -> MFMA fc_pos -> LDS transpose
// -> MFMA resblock0 -> net AoS [pt][32].
__global__ __launch_bounds__(256) void k_fused0(
    const float* __restrict__ ps,
    const ushort_t* __restrict__ wpPE, const float* __restrict__ bp,
    const ushort_t* __restrict__ wp,
    const float* __restrict__ b0, const float* __restrict__ b1,
    float* __restrict__ net)
{
  __shared__ float xlds[4][16*68];
  __shared__ float hbuf[4][16*36];
  int wave = threadIdx.x >> 6, lane = threadIdx.x & 63;
  int m = lane & 15, q = lane >> 4;
  int pbase = (blockIdx.x*4 + wave)*16;
  int pt = pbase + m;

  // ---- phase 1: positional encoding entries for this lane's A-fragment ----
  float p0 = ps[3*pt], p1 = ps[3*pt+1], p2 = ps[3*pt+2];
  float u0 = 2.f*p0 - 1.f, u1 = 2.f*p1 - 1.f, u2 = 2.f*p2 - 1.f;
  const float PIF = 3.14159265358979323846f;

  float pe[2][8];
#pragma unroll
  for (int c2 = 0; c2 < 2; c2++) {
#pragma unroll
    for (int jj = 0; jj < 8; jj++) {
      int e = c2*32 + q*8 + jj;          // PE row index (runtime via q)
      int l = (e * 43691) >> 18;         // e / 6
      int r = e - l*6;
      bool issin = (r < 3);
      int d = issin ? r : (r - 3);
      float ud = (d == 0) ? u0 : ((d == 1) ? u1 : u2);
      float xval = ldexpf(ud, l);                    // exact *2^l
      float red = xval - 2.f*rintf(0.5f*xval);       // exact mod-2
      float ang = PIF*red + (issin ? 0.f : 1.5707963267948966f);
      float v = __sinf(ang);                         // cos(x)=sin(x+pi/2)
      pe[c2][jj] = (e < 60) ? v : 0.f;               // zero-pad K 60->64
    }
  }
  bf16x8 peh[2], pel[2];
  split8(pe[0], peh[0], pel[0]);
  split8(pe[1], peh[1], pel[1]);

  // x = PE @ Wp + bp  (4 N-tiles)
  f32x4 xacc[4];
#pragma unroll
  for (int t = 0; t < 4; t++) {
    float bb = bp[t*16 + m];
    xacc[t] = (f32x4){bb,bb,bb,bb};
  }
#pragma unroll
  for (int c2 = 0; c2 < 2; c2++)
#pragma unroll
    for (int t = 0; t < 4; t++) {
      bf16x8 bh = *(const bf16x8*)(wpPE + ((size_t)((c2*4+t)*2    )*64 + lane)*8);
      bf16x8 bl = *(const bf16x8*)(wpPE + ((size_t)((c2*4+t)*2 + 1)*64 + lane)*8);
      xacc[t] = MFMA16(peh[c2], bh, xacc[t]);
      xacc[t] = MFMA16(pel[c2], bh, xacc[t]);
      xacc[t] = MFMA16(peh[c2], bl, xacc[t]);
    }

  // D-layout -> A-layout via LDS
  float* xl = xlds[wave];
#pragma unroll
  for (int t = 0; t < 4; t++)
#pragma unroll
    for (int r = 0; r < 4; r++)
      xl[(q*4+r)*68 + t*16 + m] = xacc[t][r];
  __syncthreads();

  float xv[2][8];
#pragma unroll
  for (int c2 = 0; c2 < 2; c2++)
#pragma unroll
    for (int jj = 0; jj < 8; jj++)
      xv[c2][jj] = xl[m*68 + c2*32 + q*8 + jj];

  // ---- phase 2: resblock0 via MFMA ----
  bf16x8 w0f[2][2][2], wsf[2][2][2], w1f[2][2];
#pragma unroll
  for (int c = 0; c < 2; c++)
#pragma unroll
    for (int t = 0; t < 2; t++)
#pragma unroll
      for (int e = 0; e < 2; e++) {
        w0f[c][t][e] = *(const bf16x8*)(wp + ((size_t)(((c*2+t)*2+e)    )*64 + lane)*8);
        wsf[c][t][e] = *(const bf16x8*)(wp + ((size_t)(((c*2+t)*2+e) + 8)*64 + lane)*8);
      }
#pragma unroll
  for (int t = 0; t < 2; t++)
#pragma unroll
    for (int e = 0; e < 2; e++)
      w1f[t][e] = *(const bf16x8*)(wp + ((size_t)(16 + t*2 + e)*64 + lane)*8);

  bf16x8 axh[2], axl[2], arh[2], arl[2];
#pragma unroll
  for (int c = 0; c < 2; c++) {
    float r[8];
#pragma unroll
    for (int j = 0; j < 8; j++) r[j] = fmaxf(xv[c][j], 0.f);
    split8(xv[c], axh[c], axl[c]);
    split8(r,     arh[c], arl[c]);
  }

  f32x4 hacc[2], yacc[2];
#pragma unroll
  for (int t = 0; t < 2; t++) {
    float bb0 = b0[m + 16*t], bb1 = b1[m + 16*t];
    hacc[t] = (f32x4){bb0,bb0,bb0,bb0};
    yacc[t] = (f32x4){bb1,bb1,bb1,bb1};
  }

#pragma unroll
  for (int c = 0; c < 2; c++)
#pragma unroll
    for (int t = 0; t < 2; t++) {
      hacc[t] = MFMA16(arh[c], w0f[c][t][0], hacc[t]);
      hacc[t] = MFMA16(arl[c], w0f[c][t][0], hacc[t]);
      hacc[t] = MFMA16(arh[c], w0f[c][t][1], hacc[t]);
      yacc[t] = MFMA16(axh[c], wsf[c][t][0], yacc[t]);
      yacc[t] = MFMA16(axl[c], wsf[c][t][0], yacc[t]);
      yacc[t] = MFMA16(axh[c], wsf[c][t][1], yacc[t]);
    }

  float* hb = hbuf[wave];
#pragma unroll
  for (int t = 0; t < 2; t++)
#pragma unroll
    for (int r = 0; r < 4; r++)
      hb[(q*4+r)*36 + m + 16*t] = fmaxf(hacc[t][r], 0.f);
  __syncthreads();
  float hv[8];
#pragma unroll
  for (int j = 0; j < 8; j++) hv[j] = hb[m*36 + q*8 + j];
  bf16x8 hh, hl; split8(hv, hh, hl);
#pragma unroll
  for (int t = 0; t < 2; t++) {
    yacc[t] = MFMA16(hh, w1f[t][0], yacc[t]);
    yacc[t] = MFMA16(hl, w1f[t][0], yacc[t]);
    yacc[t] = MFMA16(hh, w1f[t][1], yacc[t]);
  }

#pragma unroll
  for (int t = 0; t < 2; t++)
#pragma unroll
    for (int r = 0; r < 4; r++)
      net[(size_t)(pbase + q*4 + r)*32 + m + 16*t] = yacc[t][r];
}

// FUSED pool+stage: stage netin rows [s,e) in LDS, compute cell-max locally,
// resblock via MFMA -> netout. No k_pool, no pooled buffer.
__global__ __launch_bounds__(256) void k_stage_f(
    const float* __restrict__ netin, float* __restrict__ netout,
    const int* __restrict__ gsort, const int* __restrict__ start,
    const ushort_t* __restrict__ wp,
    const float* __restrict__ b0, const float* __restrict__ b1)
{
  __shared__ float sbuf[SROWS*36];   // staging (stride 36); reused as h-transpose
  int tid = threadIdx.x;
  int P0 = blockIdx.x*64;
  int s = start[gsort[P0]];
  int e = start[gsort[P0+63] + 1];
  int n = e - s; if (n > SROWS) n = SROWS;

  for (int idx = tid; idx < n*8; idx += 256) {
    int r = idx >> 3, c = idx & 7;
    *(f32x4*)(sbuf + r*36 + c*4) =
      *(const f32x4*)(netin + ((size_t)(s + r))*32 + c*4);
  }
  __syncthreads();

  int wave = tid >> 6, lane = tid & 63;
  int m = lane & 15, q = lane >> 4;
  int pbase = P0 + wave*16;
  int pt = pbase + m;
  int g = gsort[pt];
  int cs = start[g] - s, ce = start[g+1] - s;

  float xv[2][8];
  {
    const float* xr = sbuf + (pt - s)*36 + q*8;
    *(f32x4*)&xv[0][0] = *(const f32x4*)xr;
    *(f32x4*)&xv[0][4] = *(const f32x4*)(xr + 4);
  }
  {
    f32x4 ma = (f32x4){-INFINITY,-INFINITY,-INFINITY,-INFINITY};
    f32x4 mb = ma;
    for (int k = cs; k < ce; k++) {
      const float* rr = sbuf + k*36 + q*8;
      f32x4 va = *(const f32x4*)rr;
      f32x4 vb = *(const f32x4*)(rr + 4);
      ma.x = fmaxf(ma.x, va.x); ma.y = fmaxf(ma.y, va.y);
      ma.z = fmaxf(ma.z, va.z); ma.w = fmaxf(ma.w, va.w);
      mb.x = fmaxf(mb.x, vb.x); mb.y = fmaxf(mb.y, vb.y);
      mb.z = fmaxf(mb.z, vb.z); mb.w = fmaxf(mb.w, vb.w);
    }
    *(f32x4*)&xv[1][0] = ma;
    *(f32x4*)&xv[1][4] = mb;
  }

  bf16x8 w0f[2][2][2], wsf[2][2][2], w1f[2][2];
#pragma unroll
  for (int c = 0; c < 2; c++)
#pragma unroll
    for (int t = 0; t < 2; t++)
#pragma unroll
      for (int e2 = 0; e2 < 2; e2++) {
        w0f[c][t][e2] = *(const bf16x8*)(wp + ((size_t)(((c*2+t)*2+e2)    )*64 + lane)*8);
        wsf[c][t][e2] = *(const bf16x8*)(wp + ((size_t)(((c*2+t)*2+e2) + 8)*64 + lane)*8);
      }
#pragma unroll
  for (int t = 0; t < 2; t++)
#pragma unroll
    for (int e2 = 0; e2 < 2; e2++)
      w1f[t][e2] = *(const bf16x8*)(wp + ((size_t)(16 + t*2 + e2)*64 + lane)*8);

  bf16x8 axh[2], axl[2], arh[2], arl[2];
#pragma unroll
  for (int c = 0; c < 2; c++) {
    float r[8];
#pragma unroll
    for (int j = 0; j < 8; j++) r[j] = fmaxf(xv[c][j], 0.f);
    split8(xv[c], axh[c], axl[c]);
    split8(r,     arh[c], arl[c]);
  }

  f32x4 hacc[2], yacc[2];
#pragma unroll
  for (int t = 0; t < 2; t++) {
    float bb0 = b0[m + 16*t], bb1 = b1[m + 16*t];
    hacc[t] = (f32x4){bb0,bb0,bb0,bb0};
    yacc[t] = (f32x4){bb1,bb1,bb1,bb1};
  }

#pragma unroll
  for (int c = 0; c < 2; c++)
#pragma unroll
    for (int t = 0; t < 2; t++) {
      hacc[t] = MFMA16(arh[c], w0f[c][t][0], hacc[t]);
      hacc[t] = MFMA16(arl[c], w0f[c][t][0], hacc[t]);
      hacc[t] = MFMA16(arh[c], w0f[c][t][1], hacc[t]);
      yacc[t] = MFMA16(axh[c], wsf[c][t][0], yacc[t]);
      yacc[t] = MFMA16(axl[c], wsf[c][t][0], yacc[t]);
      yacc[t] = MFMA16(axh[c], wsf[c][t][1], yacc[t]);
    }

  __syncthreads();   // all staging reads done -> safe to reuse sbuf
  float* hb = sbuf + wave*576;
#pragma unroll
  for (int t = 0; t < 2; t++)
#pragma unroll
    for (int r = 0; r < 4; r++)
      hb[(q*4+r)*36 + m + 16*t] = fmaxf(hacc[t][r], 0.f);
  __syncthreads();
  float hv[8];
#pragma unroll
  for (int j = 0; j < 8; j++) hv[j] = hb[m*36 + q*8 + j];
  bf16x8 hh, hl; split8(hv, hh, hl);
#pragma unroll
  for (int t = 0; t < 2; t++) {
    yacc[t] = MFMA16(hh, w1f[t][0], yacc[t]);
    yacc[t] = MFMA16(hl, w1f[t][0], yacc[t]);
    yacc[t] = MFMA16(hh, w1f[t][1], yacc[t]);
  }

#pragma unroll
  for (int t = 0; t < 2; t++)
#pragma unroll
    for (int r = 0; r < 4; r++)
      netout[(size_t)(pbase + q*4 + r)*32 + m + 16*t] = yacc[t][r];
}

// FUSED pool+final+fc_c
__global__ __launch_bounds__(256) void k_final_f(
    const float* __restrict__ netin, float* __restrict__ netout,
    const int* __restrict__ gsort, const int* __restrict__ start,
    const ushort_t* __restrict__ wp, const ushort_t* __restrict__ wpc,
    const float* __restrict__ b0, const float* __restrict__ b1,
    const float* __restrict__ bc)
{
  __shared__ float sbuf[SROWS*36];
  int tid = threadIdx.x;
  int P0 = blockIdx.x*64;
  int s = start[gsort[P0]];
  int e = start[gsort[P0+63] + 1];
  int n = e - s; if (n > SROWS) n = SROWS;

  for (int idx = tid; idx < n*8; idx += 256) {
    int r = idx >> 3, c = idx & 7;
    *(f32x4*)(sbuf + r*36 + c*4) =
      *(const f32x4*)(netin + ((size_t)(s + r))*32 + c*4);
  }
  __syncthreads();

  int wave = tid >> 6, lane = tid & 63;
  int m = lane & 15, q = lane >> 4;
  int pbase = P0 + wave*16;
  int pt = pbase + m;
  int g = gsort[pt];
  int cs = start[g] - s, ce = start[g+1] - s;

  float xv[2][8];
  {
    const float* xr = sbuf + (pt - s)*36 + q*8;
    *(f32x4*)&xv[0][0] = *(const f32x4*)xr;
    *(f32x4*)&xv[0][4] = *(const f32x4*)(xr + 4);
  }
  {
    f32x4 ma = (f32x4){-INFINITY,-INFINITY,-INFINITY,-INFINITY};
    f32x4 mb = ma;
    for (int k = cs; k < ce; k++) {
      const float* rr = sbuf + k*36 + q*8;
      f32x4 va = *(const f32x4*)rr;
      f32x4 vb = *(const f32x4*)(rr + 4);
      ma.x = fmaxf(ma.x, va.x); ma.y = fmaxf(ma.y, va.y);
      ma.z = fmaxf(ma.z, va.z); ma.w = fmaxf(ma.w, va.w);
      mb.x = fmaxf(mb.x, vb.x); mb.y = fmaxf(mb.y, vb.y);
      mb.z = fmaxf(mb.z, vb.z); mb.w = fmaxf(mb.w, vb.w);
    }
    *(f32x4*)&xv[1][0] = ma;
    *(f32x4*)&xv[1][4] = mb;
  }

  bf16x8 w0f[2][2][2], wsf[2][2][2], w1f[2][2], wcf[2][2];
#pragma unroll
  for (int c = 0; c < 2; c++)
#pragma unroll
    for (int t = 0; t < 2; t++)
#pragma unroll
      for (int e2 = 0; e2 < 2; e2++) {
        w0f[c][t][e2] = *(const bf16x8*)(wp + ((size_t)(((c*2+t)*2+e2)    )*64 + lane)*8);
        wsf[c][t][e2] = *(const bf16x8*)(wp + ((size_t)(((c*2+t)*2+e2) + 8)*64 + lane)*8);
      }
#pragma unroll
  for (int t = 0; t < 2; t++)
#pragma unroll
    for (int e2 = 0; e2 < 2; e2++) {
      w1f[t][e2] = *(const bf16x8*)(wp  + ((size_t)(16 + t*2 + e2)*64 + lane)*8);
      wcf[t][e2] = *(const bf16x8*)(wpc + ((size_t)(     t*2 + e2)*64 + lane)*8);
    }

  bf16x8 axh[2], axl[2], arh[2], arl[2];
#pragma unroll
  for (int c = 0; c < 2; c++) {
    float r[8];
#pragma unroll
    for (int j = 0; j < 8; j++) r[j] = fmaxf(xv[c][j], 0.f);
    split8(xv[c], axh[c], axl[c]);
    split8(r,     arh[c], arl[c]);
  }

  f32x4 hacc[2], yacc[2];
#pragma unroll
  for (int t = 0; t < 2; t++) {
    float bb0 = b0[m + 16*t], bb1 = b1[m + 16*t];
    hacc[t] = (f32x4){bb0,bb0,bb0,bb0};
    yacc[t] = (f32x4){bb1,bb1,bb1,bb1};
  }

#pragma unroll
  for (int c = 0; c < 2; c++)
#pragma unroll
    for (int t = 0; t < 2; t++) {
      hacc[t] = MFMA16(arh[c], w0f[c][t][0], hacc[t]);
      hacc[t] = MFMA16(arl[c], w0f[c][t][0], hacc[t]);
      hacc[t] = MFMA16(arh[c], w0f[c][t][1], hacc[t]);
      yacc[t] = MFMA16(axh[c], wsf[c][t][0], yacc[t]);
      yacc[t] = MFMA16(axl[c], wsf[c][t][0], yacc[t]);
      yacc[t] = MFMA16(axh[c], wsf[c][t][1], yacc[t]);
    }

  __syncthreads();   // staging reads done -> reuse sbuf
  float* hb = sbuf + wave*576;
  float* yb = sbuf + 4*576 + wave*576;
#pragma unroll
  for (int t = 0; t < 2; t++)
#pragma unroll
    for (int r = 0; r < 4; r++)
      hb[(q*4+r)*36 + m + 16*t] = fmaxf(hacc[t][r], 0.f);
  __syncthreads();
  float hv[8];
#pragma unroll
  for (int j = 0; j < 8; j++) hv[j] = hb[m*36 + q*8 + j];
  bf16x8 hh, hl; split8(hv, hh, hl);
#pragma unroll
  for (int t = 0; t < 2; t++) {
    yacc[t] = MFMA16(hh, w1f[t][0], yacc[t]);
    yacc[t] = MFMA16(hl, w1f[t][0], yacc[t]);
    yacc[t] = MFMA16(hh, w1f[t][1], yacc[t]);
  }

  // y -> A-layout via LDS for fc_c
#pragma unroll
  for (int t = 0; t < 2; t++)
#pragma unroll
    for (int r = 0; r < 4; r++)
      yb[(q*4+r)*36 + m + 16*t] = yacc[t][r];
  __syncthreads();
  float yv[8];
#pragma unroll
  for (int j = 0; j < 8; j++) yv[j] = yb[m*36 + q*8 + j];
  bf16x8 yh, yl; split8(yv, yh, yl);

  f32x4 cacc[2];
#pragma unroll
  for (int t = 0; t < 2; t++) {
    float bb = bc[m + 16*t];
    cacc[t] = (f32x4){bb,bb,bb,bb};
    cacc[t] = MFMA16(yh, wcf[t][0], cacc[t]);
    cacc[t] = MFMA16(yl, wcf[t][0], cacc[t]);
    cacc[t] = MFMA16(yh, wcf[t][1], cacc[t]);
  }

#pragma unroll
  for (int t = 0; t < 2; t++)
#pragma unroll
    for (int r = 0; r < 4; r++)
      netout[(size_t)(pbase + q*4 + r)*32 + m + 16*t] = cacc[t][r];
}

// AoS mean -> out[b][ch][cell]; empty cells -> 0
__global__ __launch_bounds__(256) void k_mean(
    const float* __restrict__ net, const int* __restrict__ start,
    float* __restrict__ outp)
{
  int tid = blockIdx.x*256 + threadIdx.x;   // [0, BG*8)
  int c = tid >> 3, sub = tid & 7;
  int s = start[c], e = start[c+1];
  f32x4 sum = (f32x4){0.f,0.f,0.f,0.f};
  for (int k = s; k < e; k++) {
    f32x4 v = *(const f32x4*)(net + (size_t)k*32 + sub*4);
    sum.x += v.x; sum.y += v.y; sum.z += v.z; sum.w += v.w;
  }
  float inv = (e > s) ? 1.f/(float)(e - s) : 0.f;
  int b = c >> 15, cell = c & 32767;
  size_t ob = ((size_t)b << 20) + cell;
#pragma unroll
  for (int jj = 0; jj < 4; jj++) {
    int ch = sub*4 + jj;
    float v = ((const float*)&sum)[jj] * inv;
    outp[ob + ((size_t)ch << 15)] = v;
  }
}

extern "C" void kernel_launch(void* const* d_in, const int* in_sizes, int n_in,
                              void* d_out, int out_size, void* d_ws, size_t ws_size,
                              hipStream_t stream)
{
  const float* p   = (const float*)d_in[0];
  const float* Wp  = (const float*)d_in[1];
  const float* bp  = (const float*)d_in[2];
  const float* f0w = (const float*)d_in[3];
  const float* f0b = (const float*)d_in[4];
  const float* f1w = (const float*)d_in[5];
  const float* f1b = (const float*)d_in[6];
  const float* scw = (const float*)d_in[7];
  const float* wc  = (const float*)d_in[8];
  const float* bc  = (const float*)d_in[9];
  float* outp = (float*)d_out;

  char* wsb = (char*)d_ws;
  float*    netA     = (float*)wsb;                       // NPTS*32 f32 = 51.2 MB
  float*    netB     = netA + (size_t)NPTS*32;            // NPTS*32 f32 = 51.2 MB
  int*      gbuf     = (int*)(netB + (size_t)NPTS*32);    // NPTS
  int*      gsort    = gbuf + NPTS;                       // NPTS
  int*      hist     = gsort + NPTS;                      // BG
  int*      start    = hist + BG;                         // BG+1
  int*      cursor   = start + BG + 1;                    // BG
  int*      texcl    = cursor + BG;                       // BG
  int*      bsum     = texcl + BG;                        // 256
  int*      boff     = bsum + 256;                        // 256
  ushort_t* wpack    = (ushort_t*)(boff + 256);           // 120*512 ushort
  float*    p_sorted = (float*)(wpack + (size_t)120*512); // NPTS*3

  dim3 blk(256);
  dim3 gpts((NPTS + 255)/256);
  dim3 gmfma(NPTS/64);          // 6250 blocks
  dim3 gcell((BG*8)/256);       // 2048 blocks
  dim3 gscan(BG/256);           // 256 blocks

  hipMemsetAsync(hist, 0, (size_t)BG*4, stream);
  hipLaunchKernelGGL(k_hist, gpts, blk, 0, stream, p, gbuf, hist);
  hipLaunchKernelGGL(k_scanA, gscan, blk, 0, stream, hist, texcl, bsum);
  hipLaunchKernelGGL(k_scanB, dim3(1), blk, 0, stream, bsum, boff);
  hipLaunchKernelGGL(k_scanC, gscan, blk, 0, stream, texcl, boff, start, cursor);
  hipLaunchKernelGGL(k_scatter, gpts, blk, 0, stream, p, gbuf, cursor, p_sorted, gsort);
  hipLaunchKernelGGL(k_pack, dim3(120), dim3(64), 0, stream, f0w, scw, f1w, wc, Wp, wpack);
  hipLaunchKernelGGL(k_fused0, gmfma, blk, 0, stream,
                     p_sorted, wpack + (size_t)104*512, bp,
                     wpack + (size_t)0*20*512, f0b + 0*32, f1b + 0*32, netA);
  hipLaunchKernelGGL(k_stage_f, gmfma, blk, 0, stream, netA, netB, gsort, start,
                     wpack + (size_t)1*20*512, f0b + 1*32, f1b + 1*32);
  hipLaunchKernelGGL(k_stage_f, gmfma, blk, 0, stream, netB, netA, gsort, start,
                     wpack + (size_t)2*20*512, f0b + 2*32, f1b + 2*32);
  hipLaunchKernelGGL(k_stage_f, gmfma, blk, 0, stream, netA, netB, gsort, start,
                     wpack + (size_t)3*20*512, f0b + 3*32, f1b + 3*32);
  hipLaunchKernelGGL(k_final_f, gmfma, blk, 0, stream, netB, netA, gsort, start,
                     wpack + (size_t)4*20*512, wpack + (size_t)100*512,
                     f0b + 4*32, f1b + 4*32, bc);
  hipLaunchKernelGGL(k_mean, gcell, blk, 0, stream, netA, start, outp);
}